// Round 9
// baseline (1464.405 us; speedup 1.0000x reference)
//
#include <hip/hip_runtime.h>

// N=32768 rows, K=8192 codes, D=256, fp32 in, int32 out.
constexpr int D_DIM   = 256;
constexpr int N_ROWS  = 32768;
constexpr int K_CODES = 8192;
// Screen margin: RTN 1-product distance error eps <= 0.16; need TAU >= 2*eps.
constexpr float TAU   = 0.45f;

// pass-1 tiling (round-5 verified structure, hi operands only)
constexpr int BM = 128, BN = 256, STRIP = 4096, NSTRIP = 2, NCT = 16, NDC = 4;

typedef _Float16 f16x8  __attribute__((ext_vector_type(8)));
typedef __fp16   fp16x2 __attribute__((ext_vector_type(2)));
typedef float    f32x16 __attribute__((ext_vector_type(16)));

#define MFMA32(a, b, c) __builtin_amdgcn_mfma_f32_32x32x16_f16(a, b, c, 0, 0, 0)

__device__ __forceinline__ unsigned long long pack3(float v, int idx, int f) {
    return ((unsigned long long)__float_as_uint(v) << 32) |
           ((unsigned)f << 30) | (unsigned)idx;
}

// RTN split: hi = rn16(x), lo = rn16(x - hi).
__device__ __forceinline__ void cvt_rtn(const float4 a, const float4 b,
                                        uint4& hi, uint4& lo) {
    float f[8] = {a.x, a.y, a.z, a.w, b.x, b.y, b.z, b.w};
    unsigned hb[8], lb[8];
#pragma unroll
    for (int i = 0; i < 8; ++i) {
        _Float16 h = (_Float16)f[i];
        _Float16 l = (_Float16)(f[i] - (float)h);
        hb[i] = __builtin_bit_cast(unsigned short, h);
        lb[i] = __builtin_bit_cast(unsigned short, l);
    }
    hi = make_uint4(hb[0] | (hb[1] << 16), hb[2] | (hb[3] << 16),
                    hb[4] | (hb[5] << 16), hb[6] | (hb[7] << 16));
    lo = make_uint4(lb[0] | (lb[1] << 16), lb[2] | (lb[3] << 16),
                    lb[4] | (lb[5] << 16), lb[6] | (lb[7] << 16));
}

// RTZ split used by the (verified) fallback path.
__device__ __forceinline__ void cvt_granule(const float4 a, const float4 b,
                                            uint4& hi, uint4& lo) {
    fp16x2 h0 = __builtin_amdgcn_cvt_pkrtz(a.x, a.y);
    fp16x2 h1 = __builtin_amdgcn_cvt_pkrtz(a.z, a.w);
    fp16x2 h2 = __builtin_amdgcn_cvt_pkrtz(b.x, b.y);
    fp16x2 h3 = __builtin_amdgcn_cvt_pkrtz(b.z, b.w);
    fp16x2 l0 = __builtin_amdgcn_cvt_pkrtz(a.x - (float)h0.x, a.y - (float)h0.y);
    fp16x2 l1 = __builtin_amdgcn_cvt_pkrtz(a.z - (float)h1.x, a.w - (float)h1.y);
    fp16x2 l2 = __builtin_amdgcn_cvt_pkrtz(b.x - (float)h2.x, b.y - (float)h2.y);
    fp16x2 l3 = __builtin_amdgcn_cvt_pkrtz(b.z - (float)h3.x, b.w - (float)h3.y);
    hi = make_uint4(__builtin_bit_cast(unsigned, h0), __builtin_bit_cast(unsigned, h1),
                    __builtin_bit_cast(unsigned, h2), __builtin_bit_cast(unsigned, h3));
    lo = make_uint4(__builtin_bit_cast(unsigned, l0), __builtin_bit_cast(unsigned, l1),
                    __builtin_bit_cast(unsigned, l2), __builtin_bit_cast(unsigned, l3));
}

__device__ __forceinline__ void gl_lds16(const uint4* g, uint4* l) {
    __builtin_amdgcn_global_load_lds(
        (const __attribute__((address_space(1))) void*)g,
        (__attribute__((address_space(3))) void*)l, 16, 0, 0);
}

// ---------------------------------------------------------------------------
// Prep: RTN hi/lo split to blocked layouts + esqb + counter zero.
//  X: g = rb*4096 + dc*1024 + L*128 + r   (rb: 128-row block, d = dc*64+L*8)
//  E: g = cb*8192 + dc*2048 + L*256 + c   (cb: 256-code tile)
// ---------------------------------------------------------------------------
__global__ __launch_bounds__(256)
void prep_kernel(const float* __restrict__ X, const float* __restrict__ E,
                 uint4* __restrict__ Xh, uint4* __restrict__ Xl,
                 uint4* __restrict__ Eh, uint4* __restrict__ El,
                 float* __restrict__ esqb, int* __restrict__ cnt) {
    const int tid = threadIdx.x, bid = blockIdx.x;
    if (bid < 1024) {
#pragma unroll 1
        for (int it = 0; it < 4; ++it) {
            const int gid = bid * 1024 + it * 256 + tid;
            const int rb = gid >> 12, rem = gid & 4095;
            const int dc = rem >> 10, L = (rem >> 7) & 7, r = rem & 127;
            const float* p = X + (size_t)(rb * 128 + r) * D_DIM + dc * 64 + L * 8;
            const float4 a = *(const float4*)p, b = *(const float4*)(p + 4);
            uint4 hi, lo; cvt_rtn(a, b, hi, lo);
            Xh[gid] = hi; Xl[gid] = lo;
        }
    } else if (bid < 1280) {
#pragma unroll 1
        for (int it = 0; it < 4; ++it) {
            const int gid = (bid - 1024) * 1024 + it * 256 + tid;
            const int cb = gid >> 13, rem = gid & 8191;
            const int dc = rem >> 11, L = (rem >> 8) & 7, c = rem & 255;
            const float* p = E + (size_t)(cb * 256 + c) * D_DIM + dc * 64 + L * 8;
            const float4 a = *(const float4*)p, b = *(const float4*)(p + 4);
            uint4 hi, lo; cvt_rtn(a, b, hi, lo);
            Eh[gid] = hi; El[gid] = lo;
        }
    } else {
        if (bid == 1280 && tid == 0) *cnt = 0;
        const int t = (bid - 1280) * 256 + tid;
        const int gw = t >> 6, lane = t & 63;
        const float4 v = ((const float4*)(E + (size_t)gw * D_DIM))[lane];
        float s = v.x * v.x + v.y * v.y + v.z * v.z + v.w * v.w;
#pragma unroll
        for (int off = 32; off; off >>= 1) s += __shfl_down(s, off, 64);
        if (lane == 0) esqb[gw] = s + 1024.0f;
    }
}

// ---------------------------------------------------------------------------
// Pass 1: single-product (xh*eh) screen. Tracks per-row (min, idx, flag).
// Flag = exists other code with d~ < min + TAU (conservative, proven).
// ---------------------------------------------------------------------------
__global__ __launch_bounds__(256, 2)
void vq_pass1(const uint4* __restrict__ Xh, const uint4* __restrict__ Eh,
              const float* __restrict__ esqb, unsigned long long* __restrict__ res) {
    __shared__ uint4 sXh[1024];                 // 16 KB
    __shared__ uint4 sEh[2048];                 // 32 KB
    __shared__ unsigned long long slot[4][64];  // 2 KB

    const int tid  = threadIdx.x;
    const int lane = tid & 63, wv = tid >> 6, wr = wv >> 1, wc = wv & 1;
    const int l31  = lane & 31, lh = lane >> 5;
    const int wbase = wv << 6;
    const int bx = blockIdx.x, strip = blockIdx.y;
    const int cs0 = strip * STRIP;

    const uint4* Xhb = Xh + bx * 4096;
    const uint4* Ehs = Eh + (size_t)strip * NCT * 8192;

    float bestv[2][16]; int besti[2][16]; unsigned flagb = 0;
#pragma unroll
    for (int ti = 0; ti < 2; ++ti)
#pragma unroll
        for (int r = 0; r < 16; ++r) { bestv[ti][r] = 3.0e38f; besti[ti][r] = 0; }

    f32x16 acc[2][4];

#pragma unroll 1
    for (int ct = 0; ct < NCT; ++ct) {
        const uint4* Ehb = Ehs + ct * 8192;
#pragma unroll
        for (int ti = 0; ti < 2; ++ti)
#pragma unroll
            for (int tj = 0; tj < 4; ++tj)
#pragma unroll
                for (int i = 0; i < 16; ++i) acc[ti][tj][i] = 0.0f;

#pragma unroll 1
        for (int dc = 0; dc < NDC; ++dc) {
            __syncthreads();
#pragma unroll
            for (int i = 0; i < 4; ++i)
                gl_lds16(Xhb + dc * 1024 + i * 256 + tid, &sXh[i * 256 + wbase]);
#pragma unroll
            for (int i = 0; i < 8; ++i)
                gl_lds16(Ehb + dc * 2048 + i * 256 + tid, &sEh[i * 256 + wbase]);
            __syncthreads();

#pragma unroll
            for (int s = 0; s < 4; ++s) {
                const int gi = s * 2 + lh;
                f16x8 a0[2], b0[4];
#pragma unroll
                for (int ti = 0; ti < 2; ++ti)
                    a0[ti] = __builtin_bit_cast(f16x8, sXh[gi * 128 + wr * 64 + ti * 32 + l31]);
#pragma unroll
                for (int tj = 0; tj < 4; ++tj)
                    b0[tj] = __builtin_bit_cast(f16x8, sEh[gi * 256 + wc * 128 + tj * 32 + l31]);
#pragma unroll
                for (int ti = 0; ti < 2; ++ti)
#pragma unroll
                    for (int tj = 0; tj < 4; ++tj)
                        acc[ti][tj] = MFMA32(a0[ti], b0[tj], acc[ti][tj]);
            }
        }

        // epilogue: running (min, idx, flag) per row-cell
#pragma unroll
        for (int tj = 0; tj < 4; ++tj) {
            const int code = cs0 + ct * BN + wc * 128 + tj * 32 + l31;
            const float eb = esqb[code];
#pragma unroll
            for (int ti = 0; ti < 2; ++ti)
#pragma unroll
                for (int r = 0; r < 16; ++r) {
                    const float dv = fmaf(-2.0f, acc[ti][tj][r], eb);
                    const unsigned bit = 1u << (ti * 16 + r);
                    if (dv < bestv[ti][r]) {
                        if (bestv[ti][r] < dv + TAU) flagb |= bit;
                        bestv[ti][r] = dv; besti[ti][r] = code;
                    } else if (dv < bestv[ti][r] + TAU) flagb |= bit;
                }
        }
    }

    // butterfly over the 32 code-lanes; merge preserves flag semantics
#pragma unroll
    for (int ti = 0; ti < 2; ++ti)
#pragma unroll
        for (int r = 0; r < 16; ++r) {
            float v = bestv[ti][r]; int bi = besti[ti][r];
            int f = (int)((flagb >> (ti * 16 + r)) & 1u);
#pragma unroll
            for (int m = 16; m >= 1; m >>= 1) {
                const float ov = __shfl_xor(v, m, 32);
                const int   oi = __shfl_xor(bi, m, 32);
                const int   of = __shfl_xor(f, m, 32);
                f = f | of | ((fmaxf(ov, v) < fminf(ov, v) + TAU) ? 1 : 0);
                if (ov < v || (ov == v && oi < bi)) { v = ov; bi = oi; }
            }
            if (l31 == 0) {
                const int rloc = ti * 32 + (r & 3) + 8 * (r >> 2) + 4 * lh;   // 0..63
                slot[wv][rloc] = pack3(v, bi, f);
            }
        }

    __syncthreads();
    if (tid < 128) {
        const int row = tid, w2 = row >> 6, rl = row & 63;
        const unsigned long long A = slot[w2 * 2 + 0][rl];
        const unsigned long long B = slot[w2 * 2 + 1][rl];
        const float va = __uint_as_float((unsigned)(A >> 32));
        const float vb = __uint_as_float((unsigned)(B >> 32));
        const int ia = (int)(A & 0x1FFF), ib = (int)(B & 0x1FFF);
        const int fa = (int)((A >> 30) & 1), fb = (int)((B >> 30) & 1);
        const bool bwin = (vb < va) || (vb == va && ib < ia);
        const float v = bwin ? vb : va;
        const int  ix = bwin ? ib : ia;
        const int  f  = fa | fb | ((fmaxf(va, vb) < fminf(va, vb) + TAU) ? 1 : 0);
        res[(size_t)strip * N_ROWS + bx * 128 + row] = pack3(v, ix, f);
    }
}

// ---------------------------------------------------------------------------
// Merge strips: clean rows -> out; ambiguous rows -> list, res[row] = max.
// ---------------------------------------------------------------------------
__global__ void merge_kernel(unsigned long long* __restrict__ res, int* __restrict__ out,
                             int* __restrict__ cnt, int* __restrict__ list) {
    const int row = blockIdx.x * 256 + threadIdx.x;
    const unsigned long long A = res[row], B = res[N_ROWS + row];
    const float va = __uint_as_float((unsigned)(A >> 32));
    const float vb = __uint_as_float((unsigned)(B >> 32));
    const int ia = (int)(A & 0x1FFF), ib = (int)(B & 0x1FFF);
    const int fa = (int)((A >> 30) & 1), fb = (int)((B >> 30) & 1);
    const bool bwin = (vb < va) || (vb == va && ib < ia);
    const float wv = bwin ? vb : va, lv = bwin ? va : vb;
    const int ix = bwin ? ib : ia;
    const int f = fa | fb | ((lv < wv + TAU) ? 1 : 0);
    out[row] = ix;
    if (f) {
        const int p = atomicAdd(cnt, 1);
        list[p] = row;
        res[row] = ~0ull;
    }
}

// ---------------------------------------------------------------------------
// Refine v2: flagged rows, exact 3-product over all codes, ILP-4.
// Block = 32 gathered rows x 4096-code strip (grid 1024 x 2, uniform exit).
// A hi/lo staged once (32 KB LDS). Each wave: 1024 codes in 8 passes of 128
// (4 independent 32x32 acc tiles). Per K-step: 8 coalesced B loads + 2
// ds_read + 12 MFMA, no barriers -> compiler pipelines across K-steps.
// ---------------------------------------------------------------------------
__global__ __launch_bounds__(256, 1)
void refine_kernel(const uint4* __restrict__ Xh, const uint4* __restrict__ Xl,
                   const uint4* __restrict__ Eh, const uint4* __restrict__ El,
                   const float* __restrict__ esqb, const int* __restrict__ cnt,
                   const int* __restrict__ list, unsigned long long* __restrict__ res0) {
    __shared__ int  rows_s[32];
    __shared__ uint4 sAh[1024], sAl[1024];   // 32 KB

    const int n = *cnt;
    const int base = blockIdx.x * 32;
    if (base >= n) return;                   // block-uniform
    const int tid = threadIdx.x;
    if (tid < 32) { const int j = base + tid; rows_s[tid] = list[j < n ? j : base]; }
    __syncthreads();

    // gather A: granule slot Lg (=dc*8+L, 0..31) x row slot rr (0..31)
#pragma unroll
    for (int jj = 0; jj < 4; ++jj) {
        const int gg = jj * 256 + tid, Lg = gg >> 5, rr = gg & 31;
        const int row = rows_s[rr];
        const int g = (row >> 7) * 4096 + (Lg >> 3) * 1024 + (Lg & 7) * 128 + (row & 127);
        sAh[Lg * 32 + rr] = Xh[g]; sAl[Lg * 32 + rr] = Xl[g];
    }
    __syncthreads();

    const int lane = tid & 63, wv = tid >> 6, l31 = lane & 31, lh = lane >> 5;
    const int cbase = blockIdx.y * 4096 + wv * 1024;

    float bestv[16]; int besti[16];
#pragma unroll
    for (int r = 0; r < 16; ++r) { bestv[r] = 3.0e38f; besti[r] = 0; }

#pragma unroll 1
    for (int ps = 0; ps < 8; ++ps) {         // 8 passes of 128 codes
        const int c0 = cbase + ps * 128;
        f32x16 acc[4];
#pragma unroll
        for (int tj = 0; tj < 4; ++tj)
#pragma unroll
            for (int i = 0; i < 16; ++i) acc[tj][i] = 0.0f;

#pragma unroll
        for (int ks = 0; ks < 16; ++ks) {
            const int Lg = ks * 2 + lh;
            f16x8 b0[4], b1[4];
#pragma unroll
            for (int tj = 0; tj < 4; ++tj) {
                const int c = c0 + tj * 32 + l31;
                const int eg = (c >> 8) * 8192 + (Lg >> 3) * 2048 + (Lg & 7) * 256 + (c & 255);
                b0[tj] = __builtin_bit_cast(f16x8, Eh[eg]);
                b1[tj] = __builtin_bit_cast(f16x8, El[eg]);
            }
            const f16x8 a0 = __builtin_bit_cast(f16x8, sAh[Lg * 32 + l31]);
            const f16x8 a1 = __builtin_bit_cast(f16x8, sAl[Lg * 32 + l31]);
#pragma unroll
            for (int tj = 0; tj < 4; ++tj) acc[tj] = MFMA32(a1, b0[tj], acc[tj]);
#pragma unroll
            for (int tj = 0; tj < 4; ++tj) acc[tj] = MFMA32(a0, b1[tj], acc[tj]);
#pragma unroll
            for (int tj = 0; tj < 4; ++tj) acc[tj] = MFMA32(a0, b0[tj], acc[tj]);
        }

#pragma unroll
        for (int tj = 0; tj < 4; ++tj) {
            const int c = c0 + tj * 32 + l31;
            const float eb = esqb[c];
#pragma unroll
            for (int r = 0; r < 16; ++r) {
                const float dv = fmaf(-2.0f, acc[tj][r], eb);
                if (dv < bestv[r]) { bestv[r] = dv; besti[r] = c; }
            }
        }
    }

#pragma unroll
    for (int r = 0; r < 16; ++r) {
        float v = bestv[r]; int bi = besti[r];
#pragma unroll
        for (int m = 16; m >= 1; m >>= 1) {
            const float ov = __shfl_xor(v, m, 32);
            const int   oi = __shfl_xor(bi, m, 32);
            if (ov < v || (ov == v && oi < bi)) { v = ov; bi = oi; }
        }
        if (l31 == 0) {
            const int rl = (r & 3) + 8 * (r >> 2) + 4 * lh;   // 0..31
            atomicMin(&res0[rows_s[rl]],
                      ((unsigned long long)__float_as_uint(v) << 32) | (unsigned)bi);
        }
    }
}

// ---------------------------------------------------------------------------
__global__ void finalize_kernel(const unsigned long long* __restrict__ res0,
                                const int* __restrict__ cnt, const int* __restrict__ list,
                                int* __restrict__ out) {
    const int i = blockIdx.x * 256 + threadIdx.x;
    if (i < *cnt) {
        const int row = list[i];
        out[row] = (int)(res0[row] & 0xFFFFFFFFull);
    }
}

// ---------------------------------------------------------------------------
// Fallback (round-4 verified): in-loop split, for small ws_size.
// ---------------------------------------------------------------------------
__global__ void prologue_fb(const float* __restrict__ E, float* __restrict__ esqb,
                            unsigned long long* __restrict__ packed) {
    const int t = blockIdx.x * 256 + threadIdx.x;
    if (t < N_ROWS) packed[t] = ~0ull;
    const int gw = t >> 6, lane = t & 63;
    const float4 v = ((const float4*)(E + (size_t)gw * D_DIM))[lane];
    float s = v.x * v.x + v.y * v.y + v.z * v.z + v.w * v.w;
#pragma unroll
    for (int off = 32; off; off >>= 1) s += __shfl_down(s, off, 64);
    if (lane == 0) esqb[gw] = s + 1024.0f;
}

__global__ __launch_bounds__(256, 2)
void vq_mfma_fallback(const float* __restrict__ X, const float* __restrict__ E,
                      const float* __restrict__ esqb,
                      unsigned long long* __restrict__ packed) {
    __shared__ uint4 fXh[128 * 8], fXl[128 * 8];
    __shared__ uint4 fEh[128 * 8], fEl[128 * 8];
    __shared__ float fEsq[2048];

    const int tid  = threadIdx.x;
    const int lane = tid & 63;
    const int wv   = tid >> 6;
    const int wr   = wv >> 1, wc = wv & 1;
    const int l31  = lane & 31;
    const int lh   = lane >> 5;
    const int row0 = blockIdx.x * 128;
    const int cs0  = blockIdx.y * 2048;

#pragma unroll
    for (int i = 0; i < 8; ++i) fEsq[tid + 256 * i] = esqb[cs0 + tid + 256 * i];

    const int sr = tid >> 3, sg = tid & 7;

    float best[2][16]; int bidx[2][16];
#pragma unroll
    for (int ti = 0; ti < 2; ++ti)
#pragma unroll
        for (int r = 0; r < 16; ++r) { best[ti][r] = 3.0e38f; bidx[ti][r] = 0; }

    f32x16 acc[2][2];

#pragma unroll 1
    for (int ct = 0; ct < 16; ++ct) {
#pragma unroll
        for (int ti = 0; ti < 2; ++ti)
#pragma unroll
            for (int tj = 0; tj < 2; ++tj)
#pragma unroll
                for (int i = 0; i < 16; ++i) acc[ti][tj][i] = 0.0f;

#pragma unroll 1
        for (int dc = 0; dc < 4; ++dc) {
            __syncthreads();
#pragma unroll
            for (int i = 0; i < 4; ++i) {
                const int r = 32 * i + sr;
                const float* p = X + (size_t)(row0 + r) * D_DIM + dc * 64 + sg * 8;
                const float4 a = *(const float4*)p, b = *(const float4*)(p + 4);
                uint4 hi, lo; cvt_granule(a, b, hi, lo);
                const int o = r * 8 + (sg ^ (r & 7));
                fXh[o] = hi; fXl[o] = lo;
            }
#pragma unroll
            for (int i = 0; i < 4; ++i) {
                const int r = 32 * i + sr;
                const float* p = E + (size_t)(cs0 + ct * 128 + r) * D_DIM + dc * 64 + sg * 8;
                const float4 a = *(const float4*)p, b = *(const float4*)(p + 4);
                uint4 hi, lo; cvt_granule(a, b, hi, lo);
                const int o = r * 8 + (sg ^ (r & 7));
                fEh[o] = hi; fEl[o] = lo;
            }
            __syncthreads();

#pragma unroll
            for (int s = 0; s < 4; ++s) {
                const int gi = s * 2 + lh;
                f16x8 axh[2], axl[2], beh[2], bel[2];
#pragma unroll
                for (int ti = 0; ti < 2; ++ti) {
                    const int r = wr * 64 + ti * 32 + l31;
                    const int o = r * 8 + (gi ^ (r & 7));
                    axh[ti] = __builtin_bit_cast(f16x8, fXh[o]);
                    axl[ti] = __builtin_bit_cast(f16x8, fXl[o]);
                }
#pragma unroll
                for (int tj = 0; tj < 2; ++tj) {
                    const int c = wc * 64 + tj * 32 + l31;
                    const int o = c * 8 + (gi ^ (c & 7));
                    beh[tj] = __builtin_bit_cast(f16x8, fEh[o]);
                    bel[tj] = __builtin_bit_cast(f16x8, fEl[o]);
                }
#pragma unroll
                for (int ti = 0; ti < 2; ++ti)
#pragma unroll
                    for (int tj = 0; tj < 2; ++tj) {
                        acc[ti][tj] = MFMA32(axl[ti], beh[tj], acc[ti][tj]);
                        acc[ti][tj] = MFMA32(axh[ti], bel[tj], acc[ti][tj]);
                        acc[ti][tj] = MFMA32(axh[ti], beh[tj], acc[ti][tj]);
                    }
            }
        }

#pragma unroll
        for (int tj = 0; tj < 2; ++tj) {
            const int cloc = ct * 128 + wc * 64 + tj * 32 + l31;
            const float eb = fEsq[cloc];
            const int  code = cs0 + cloc;
#pragma unroll
            for (int ti = 0; ti < 2; ++ti)
#pragma unroll
                for (int r = 0; r < 16; ++r) {
                    const float dv = fmaf(-2.0f, acc[ti][tj][r], eb);
                    if (dv < best[ti][r]) { best[ti][r] = dv; bidx[ti][r] = code; }
                }
        }
    }

#pragma unroll
    for (int ti = 0; ti < 2; ++ti)
#pragma unroll
        for (int r = 0; r < 16; ++r) {
            float b = best[ti][r]; int bi = bidx[ti][r];
#pragma unroll
            for (int m = 16; m >= 1; m >>= 1) {
                const float ov = __shfl_xor(b, m, 32);
                const int   oi = __shfl_xor(bi, m, 32);
                if (ov < b || (ov == b && oi < bi)) { b = ov; bi = oi; }
            }
            if (l31 == 0) {
                const int row = row0 + wr * 64 + ti * 32 + (r & 3) + 8 * (r >> 2) + 4 * lh;
                const unsigned long long p =
                    ((unsigned long long)__float_as_uint(b) << 32) | (unsigned)bi;
                atomicMin(&packed[row], p);
            }
        }
}

__global__ void finish_fb(const unsigned long long* __restrict__ packed,
                          int* __restrict__ out) {
    const int i = blockIdx.x * 256 + threadIdx.x;
    out[i] = (int)(unsigned)(packed[i] & 0xffffffffull);
}

// ---------------------------------------------------------------------------
extern "C" void kernel_launch(void* const* d_in, const int* in_sizes, int n_in,
                              void* d_out, int out_size, void* d_ws, size_t ws_size,
                              hipStream_t stream) {
    const float* X = (const float*)d_in[0];    // [32768, 256]
    const float* E = (const float*)d_in[1];    // [8192, 256]
    char* ws = (char*)d_ws;
    int* out = (int*)d_out;

    float* esqb = (float*)ws;                                         // 32 KB
    unsigned long long* res = (unsigned long long*)(ws + 32768);      // 512 KB (2 strips)
    int* cnt  = (int*)(ws + 557056);                                  // 16 B
    int* list = (int*)(ws + 557072);                                  // 128 KB
    const size_t base = 1048576;                                      // 1 MB
    const size_t szX  = (size_t)N_ROWS * D_DIM * 2;                   // 16 MB per half
    const size_t szE  = (size_t)K_CODES * D_DIM * 2;                  // 4 MB per half
    const size_t need = base + 2 * szX + 2 * szE;                     // ~42 MB

    if (ws_size >= need) {
        uint4* Xh = (uint4*)(ws + base);
        uint4* Xl = (uint4*)(ws + base + szX);
        uint4* Eh = (uint4*)(ws + base + 2 * szX);
        uint4* El = (uint4*)(ws + base + 2 * szX + szE);
        prep_kernel<<<dim3(3328), dim3(256), 0, stream>>>(X, E, Xh, Xl, Eh, El, esqb, cnt);
        vq_pass1<<<dim3(N_ROWS / BM, NSTRIP), dim3(256), 0, stream>>>(Xh, Eh, esqb, res);
        merge_kernel<<<dim3(N_ROWS / 256), dim3(256), 0, stream>>>(res, out, cnt, list);
        refine_kernel<<<dim3(1024, 2), dim3(256), 0, stream>>>(Xh, Xl, Eh, El, esqb,
                                                               cnt, list, res);
        finalize_kernel<<<dim3(N_ROWS / 256), dim3(256), 0, stream>>>(res, cnt, list, out);
    } else {
        unsigned long long* packed = (unsigned long long*)(ws + 32768);
        prologue_fb<<<dim3(2048), dim3(256), 0, stream>>>(E, esqb, packed);
        vq_mfma_fallback<<<dim3(N_ROWS / 128, 4), dim3(256), 0, stream>>>(X, E, esqb, packed);
        finish_fb<<<dim3(N_ROWS / 256), dim3(256), 0, stream>>>(packed, out);
    }
}

// Round 10
// 400.115 us; speedup vs baseline: 3.6600x; 3.6600x over previous
//
#include <hip/hip_runtime.h>

// N=32768 rows, K=8192 codes, D=256, fp32 in, int32 out.
constexpr int D_DIM   = 256;
constexpr int N_ROWS  = 32768;
constexpr int K_CODES = 8192;
// Screen margin: RTN 1-product distance error eps <= ~0.16; need TAU >= 2*eps.
constexpr float TAU   = 0.45f;

// pass-1 tiling (round-5 verified structure, hi operands only)
constexpr int BM = 128, BN = 256, STRIP = 4096, NSTRIP = 2, NCT = 16, NDC = 4;

typedef _Float16 f16x8  __attribute__((ext_vector_type(8)));
typedef __fp16   fp16x2 __attribute__((ext_vector_type(2)));
typedef float    f32x16 __attribute__((ext_vector_type(16)));

#define MFMA32(a, b, c) __builtin_amdgcn_mfma_f32_32x32x16_f16(a, b, c, 0, 0, 0)

__device__ __forceinline__ unsigned long long pack2(float v, int idx) {
    return ((unsigned long long)__float_as_uint(v) << 32) | (unsigned)idx;
}

// RTN split: hi = rn16(x), lo = rn16(x - hi).
__device__ __forceinline__ void cvt_rtn(const float4 a, const float4 b,
                                        uint4& hi, uint4& lo) {
    float f[8] = {a.x, a.y, a.z, a.w, b.x, b.y, b.z, b.w};
    unsigned hb[8], lb[8];
#pragma unroll
    for (int i = 0; i < 8; ++i) {
        _Float16 h = (_Float16)f[i];
        _Float16 l = (_Float16)(f[i] - (float)h);
        hb[i] = __builtin_bit_cast(unsigned short, h);
        lb[i] = __builtin_bit_cast(unsigned short, l);
    }
    hi = make_uint4(hb[0] | (hb[1] << 16), hb[2] | (hb[3] << 16),
                    hb[4] | (hb[5] << 16), hb[6] | (hb[7] << 16));
    lo = make_uint4(lb[0] | (lb[1] << 16), lb[2] | (lb[3] << 16),
                    lb[4] | (lb[5] << 16), lb[6] | (lb[7] << 16));
}

// RTZ split used by the (verified) fallback path.
__device__ __forceinline__ void cvt_granule(const float4 a, const float4 b,
                                            uint4& hi, uint4& lo) {
    fp16x2 h0 = __builtin_amdgcn_cvt_pkrtz(a.x, a.y);
    fp16x2 h1 = __builtin_amdgcn_cvt_pkrtz(a.z, a.w);
    fp16x2 h2 = __builtin_amdgcn_cvt_pkrtz(b.x, b.y);
    fp16x2 h3 = __builtin_amdgcn_cvt_pkrtz(b.z, b.w);
    fp16x2 l0 = __builtin_amdgcn_cvt_pkrtz(a.x - (float)h0.x, a.y - (float)h0.y);
    fp16x2 l1 = __builtin_amdgcn_cvt_pkrtz(a.z - (float)h1.x, a.w - (float)h1.y);
    fp16x2 l2 = __builtin_amdgcn_cvt_pkrtz(b.x - (float)h2.x, b.y - (float)h2.y);
    fp16x2 l3 = __builtin_amdgcn_cvt_pkrtz(b.z - (float)h3.x, b.w - (float)h3.y);
    hi = make_uint4(__builtin_bit_cast(unsigned, h0), __builtin_bit_cast(unsigned, h1),
                    __builtin_bit_cast(unsigned, h2), __builtin_bit_cast(unsigned, h3));
    lo = make_uint4(__builtin_bit_cast(unsigned, l0), __builtin_bit_cast(unsigned, l1),
                    __builtin_bit_cast(unsigned, l2), __builtin_bit_cast(unsigned, l3));
}

__device__ __forceinline__ void gl_lds16(const uint4* g, uint4* l) {
    __builtin_amdgcn_global_load_lds(
        (const __attribute__((address_space(1))) void*)g,
        (__attribute__((address_space(3))) void*)l, 16, 0, 0);
}

// ---------------------------------------------------------------------------
// Prep: RTN hi/lo split to blocked layouts + esqb + counter zero.
//  X: g = rb*4096 + dc*1024 + L*128 + r   (rb: 128-row block, d = dc*64+L*8)
//  E: g = cb*8192 + dc*2048 + L*256 + c   (cb: 256-code tile)
// ---------------------------------------------------------------------------
__global__ __launch_bounds__(256)
void prep_kernel(const float* __restrict__ X, const float* __restrict__ E,
                 uint4* __restrict__ Xh, uint4* __restrict__ Xl,
                 uint4* __restrict__ Eh, uint4* __restrict__ El,
                 float* __restrict__ esqb, int* __restrict__ cnt) {
    const int tid = threadIdx.x, bid = blockIdx.x;
    if (bid < 1024) {
#pragma unroll 1
        for (int it = 0; it < 4; ++it) {
            const int gid = bid * 1024 + it * 256 + tid;
            const int rb = gid >> 12, rem = gid & 4095;
            const int dc = rem >> 10, L = (rem >> 7) & 7, r = rem & 127;
            const float* p = X + (size_t)(rb * 128 + r) * D_DIM + dc * 64 + L * 8;
            const float4 a = *(const float4*)p, b = *(const float4*)(p + 4);
            uint4 hi, lo; cvt_rtn(a, b, hi, lo);
            Xh[gid] = hi; Xl[gid] = lo;
        }
    } else if (bid < 1280) {
#pragma unroll 1
        for (int it = 0; it < 4; ++it) {
            const int gid = (bid - 1024) * 1024 + it * 256 + tid;
            const int cb = gid >> 13, rem = gid & 8191;
            const int dc = rem >> 11, L = (rem >> 8) & 7, c = rem & 255;
            const float* p = E + (size_t)(cb * 256 + c) * D_DIM + dc * 64 + L * 8;
            const float4 a = *(const float4*)p, b = *(const float4*)(p + 4);
            uint4 hi, lo; cvt_rtn(a, b, hi, lo);
            Eh[gid] = hi; El[gid] = lo;
        }
    } else {
        if (bid == 1280 && tid == 0) *cnt = 0;
        const int t = (bid - 1280) * 256 + tid;
        const int gw = t >> 6, lane = t & 63;
        const float4 v = ((const float4*)(E + (size_t)gw * D_DIM))[lane];
        float s = v.x * v.x + v.y * v.y + v.z * v.z + v.w * v.w;
#pragma unroll
        for (int off = 32; off; off >>= 1) s += __shfl_down(s, off, 64);
        if (lane == 0) esqb[gw] = s + 1024.0f;
    }
}

// ---------------------------------------------------------------------------
// Pass 1: single-product (xh*eh) screen with EXACT top-2 tracking.
// Per row cell: (best, idx) + second-best value. Tournament merges keep the
// true top-2 (m1 = min; m2 = min(max(a1,b1), a2, b2)). Flag computed only
// against the FINAL top-2 (round-9 running-min flag over-flagged ~100%).
// ---------------------------------------------------------------------------
__global__ __launch_bounds__(256, 2)
void vq_pass1(const uint4* __restrict__ Xh, const uint4* __restrict__ Eh,
              const float* __restrict__ esqb,
              unsigned long long* __restrict__ res, float* __restrict__ res2) {
    __shared__ uint4 sXh[1024];                 // 16 KB
    __shared__ uint4 sEh[2048];                 // 32 KB
    __shared__ unsigned long long slot[4][64];  // 2 KB
    __shared__ float slot2[4][64];              // 1 KB

    const int tid  = threadIdx.x;
    const int lane = tid & 63, wv = tid >> 6, wr = wv >> 1, wc = wv & 1;
    const int l31  = lane & 31, lh = lane >> 5;
    const int wbase = wv << 6;
    const int bx = blockIdx.x, strip = blockIdx.y;
    const int cs0 = strip * STRIP;

    const uint4* Xhb = Xh + bx * 4096;
    const uint4* Ehs = Eh + (size_t)strip * NCT * 8192;

    float bestv[2][16], best2[2][16]; int besti[2][16];
#pragma unroll
    for (int ti = 0; ti < 2; ++ti)
#pragma unroll
        for (int r = 0; r < 16; ++r) {
            bestv[ti][r] = 3.0e38f; best2[ti][r] = 3.0e38f; besti[ti][r] = 0;
        }

    f32x16 acc[2][4];

#pragma unroll 1
    for (int ct = 0; ct < NCT; ++ct) {
        const uint4* Ehb = Ehs + ct * 8192;
#pragma unroll
        for (int ti = 0; ti < 2; ++ti)
#pragma unroll
            for (int tj = 0; tj < 4; ++tj)
#pragma unroll
                for (int i = 0; i < 16; ++i) acc[ti][tj][i] = 0.0f;

#pragma unroll 1
        for (int dc = 0; dc < NDC; ++dc) {
            __syncthreads();
#pragma unroll
            for (int i = 0; i < 4; ++i)
                gl_lds16(Xhb + dc * 1024 + i * 256 + tid, &sXh[i * 256 + wbase]);
#pragma unroll
            for (int i = 0; i < 8; ++i)
                gl_lds16(Ehb + dc * 2048 + i * 256 + tid, &sEh[i * 256 + wbase]);
            __syncthreads();

#pragma unroll
            for (int s = 0; s < 4; ++s) {
                const int gi = s * 2 + lh;
                f16x8 a0[2], b0[4];
#pragma unroll
                for (int ti = 0; ti < 2; ++ti)
                    a0[ti] = __builtin_bit_cast(f16x8, sXh[gi * 128 + wr * 64 + ti * 32 + l31]);
#pragma unroll
                for (int tj = 0; tj < 4; ++tj)
                    b0[tj] = __builtin_bit_cast(f16x8, sEh[gi * 256 + wc * 128 + tj * 32 + l31]);
#pragma unroll
                for (int ti = 0; ti < 2; ++ti)
#pragma unroll
                    for (int tj = 0; tj < 4; ++tj)
                        acc[ti][tj] = MFMA32(a0[ti], b0[tj], acc[ti][tj]);
            }
        }

        // epilogue: exact running top-2 per row-cell (codes ascending)
#pragma unroll
        for (int tj = 0; tj < 4; ++tj) {
            const int code = cs0 + ct * BN + wc * 128 + tj * 32 + l31;
            const float eb = esqb[code];
#pragma unroll
            for (int ti = 0; ti < 2; ++ti)
#pragma unroll
                for (int r = 0; r < 16; ++r) {
                    const float dv = fmaf(-2.0f, acc[ti][tj][r], eb);
                    if (dv < bestv[ti][r]) {
                        best2[ti][r] = bestv[ti][r];
                        bestv[ti][r] = dv; besti[ti][r] = code;
                    } else if (dv < best2[ti][r]) {
                        best2[ti][r] = dv;
                    }
                }
        }
    }

    // butterfly over the 32 code-lanes, exact top-2 merge
#pragma unroll
    for (int ti = 0; ti < 2; ++ti)
#pragma unroll
        for (int r = 0; r < 16; ++r) {
            float v = bestv[ti][r], v2 = best2[ti][r]; int bi = besti[ti][r];
#pragma unroll
            for (int m = 16; m >= 1; m >>= 1) {
                const float ov  = __shfl_xor(v, m, 32);
                const float ov2 = __shfl_xor(v2, m, 32);
                const int   oi  = __shfl_xor(bi, m, 32);
                const float nb2 = fminf(fminf(v2, ov2), fmaxf(v, ov));
                if (ov < v || (ov == v && oi < bi)) { v = ov; bi = oi; }
                v2 = nb2;
            }
            if (l31 == 0) {
                const int rloc = ti * 32 + (r & 3) + 8 * (r >> 2) + 4 * lh;   // 0..63
                slot[wv][rloc] = pack2(v, bi);
                slot2[wv][rloc] = v2;
            }
        }

    __syncthreads();
    if (tid < 128) {
        const int row = tid, w2 = row >> 6, rl = row & 63;
        const unsigned long long A = slot[w2 * 2 + 0][rl];
        const unsigned long long B = slot[w2 * 2 + 1][rl];
        const float v2a = slot2[w2 * 2 + 0][rl], v2b = slot2[w2 * 2 + 1][rl];
        const float va = __uint_as_float((unsigned)(A >> 32));
        const float vb = __uint_as_float((unsigned)(B >> 32));
        const int ia = (int)(A & 0xFFFFFFFFull), ib = (int)(B & 0xFFFFFFFFull);
        const bool bwin = (vb < va) || (vb == va && ib < ia);
        const float v = bwin ? vb : va;
        const int  ix = bwin ? ib : ia;
        const float v2 = fminf(fminf(v2a, v2b), fmaxf(va, vb));
        res [(size_t)strip * N_ROWS + bx * 128 + row] = pack2(v, ix);
        res2[(size_t)strip * N_ROWS + bx * 128 + row] = v2;
    }
}

// ---------------------------------------------------------------------------
// Merge strips (exact top-2): clean rows -> out; ambiguous -> list, res=max.
// ---------------------------------------------------------------------------
__global__ void merge_kernel(unsigned long long* __restrict__ res,
                             const float* __restrict__ res2, int* __restrict__ out,
                             int* __restrict__ cnt, int* __restrict__ list) {
    const int row = blockIdx.x * 256 + threadIdx.x;
    const unsigned long long A = res[row], B = res[N_ROWS + row];
    const float v2a = res2[row], v2b = res2[N_ROWS + row];
    const float va = __uint_as_float((unsigned)(A >> 32));
    const float vb = __uint_as_float((unsigned)(B >> 32));
    const int ia = (int)(A & 0xFFFFFFFFull), ib = (int)(B & 0xFFFFFFFFull);
    const bool bwin = (vb < va) || (vb == va && ib < ia);
    const float best = bwin ? vb : va;
    const int  ix = bwin ? ib : ia;
    const float b2 = fminf(fminf(v2a, v2b), fmaxf(va, vb));
    out[row] = ix;
    if (b2 < best + TAU) {
        const int p = atomicAdd(cnt, 1);
        list[p] = row;
        res[row] = ~0ull;
    }
}

// ---------------------------------------------------------------------------
// Refine: flagged rows, exact 3-product over all codes.
// Block = 32 gathered rows x 1024-code strip (grid 1024 x 8): ~8x the TLP of
// round 9 to hide B-load latency. A hi/lo staged once (32 KB LDS); per wave
// 256 codes = 2 passes of 128 (4 independent 32x32 acc tiles, ILP 4).
// ---------------------------------------------------------------------------
__global__ __launch_bounds__(256, 1)
void refine_kernel(const uint4* __restrict__ Xh, const uint4* __restrict__ Xl,
                   const uint4* __restrict__ Eh, const uint4* __restrict__ El,
                   const float* __restrict__ esqb, const int* __restrict__ cnt,
                   const int* __restrict__ list, unsigned long long* __restrict__ res0) {
    __shared__ int  rows_s[32];
    __shared__ uint4 sAh[1024], sAl[1024];   // 32 KB

    const int n = *cnt;
    const int base = blockIdx.x * 32;
    if (base >= n) return;                   // block-uniform
    const int tid = threadIdx.x;
    if (tid < 32) { const int j = base + tid; rows_s[tid] = list[j < n ? j : base]; }
    __syncthreads();

    // gather A: granule slot Lg (=dc*8+L, 0..31) x row slot rr (0..31)
#pragma unroll
    for (int jj = 0; jj < 4; ++jj) {
        const int gg = jj * 256 + tid, Lg = gg >> 5, rr = gg & 31;
        const int row = rows_s[rr];
        const int g = (row >> 7) * 4096 + (Lg >> 3) * 1024 + (Lg & 7) * 128 + (row & 127);
        sAh[Lg * 32 + rr] = Xh[g]; sAl[Lg * 32 + rr] = Xl[g];
    }
    __syncthreads();

    const int lane = tid & 63, wv = tid >> 6, l31 = lane & 31, lh = lane >> 5;
    const int cbase = blockIdx.y * 1024 + wv * 256;

    float bestv[16]; int besti[16];
#pragma unroll
    for (int r = 0; r < 16; ++r) { bestv[r] = 3.0e38f; besti[r] = 0; }

#pragma unroll 1
    for (int ps = 0; ps < 2; ++ps) {         // 2 passes of 128 codes
        const int c0 = cbase + ps * 128;
        f32x16 acc[4];
#pragma unroll
        for (int tj = 0; tj < 4; ++tj)
#pragma unroll
            for (int i = 0; i < 16; ++i) acc[tj][i] = 0.0f;

#pragma unroll
        for (int ks = 0; ks < 16; ++ks) {
            const int Lg = ks * 2 + lh;
            f16x8 b0[4], b1[4];
#pragma unroll
            for (int tj = 0; tj < 4; ++tj) {
                const int c = c0 + tj * 32 + l31;
                const int eg = (c >> 8) * 8192 + (Lg >> 3) * 2048 + (Lg & 7) * 256 + (c & 255);
                b0[tj] = __builtin_bit_cast(f16x8, Eh[eg]);
                b1[tj] = __builtin_bit_cast(f16x8, El[eg]);
            }
            const f16x8 a0 = __builtin_bit_cast(f16x8, sAh[Lg * 32 + l31]);
            const f16x8 a1 = __builtin_bit_cast(f16x8, sAl[Lg * 32 + l31]);
#pragma unroll
            for (int tj = 0; tj < 4; ++tj) acc[tj] = MFMA32(a1, b0[tj], acc[tj]);
#pragma unroll
            for (int tj = 0; tj < 4; ++tj) acc[tj] = MFMA32(a0, b1[tj], acc[tj]);
#pragma unroll
            for (int tj = 0; tj < 4; ++tj) acc[tj] = MFMA32(a0, b0[tj], acc[tj]);
        }

#pragma unroll
        for (int tj = 0; tj < 4; ++tj) {
            const int c = c0 + tj * 32 + l31;
            const float eb = esqb[c];
#pragma unroll
            for (int r = 0; r < 16; ++r) {
                const float dv = fmaf(-2.0f, acc[tj][r], eb);
                if (dv < bestv[r]) { bestv[r] = dv; besti[r] = c; }
            }
        }
    }

#pragma unroll
    for (int r = 0; r < 16; ++r) {
        float v = bestv[r]; int bi = besti[r];
#pragma unroll
        for (int m = 16; m >= 1; m >>= 1) {
            const float ov = __shfl_xor(v, m, 32);
            const int   oi = __shfl_xor(bi, m, 32);
            if (ov < v || (ov == v && oi < bi)) { v = ov; bi = oi; }
        }
        if (l31 == 0) {
            const int rl = (r & 3) + 8 * (r >> 2) + 4 * lh;   // 0..31
            atomicMin(&res0[rows_s[rl]],
                      ((unsigned long long)__float_as_uint(v) << 32) | (unsigned)bi);
        }
    }
}

// ---------------------------------------------------------------------------
__global__ void finalize_kernel(const unsigned long long* __restrict__ res0,
                                const int* __restrict__ cnt, const int* __restrict__ list,
                                int* __restrict__ out) {
    const int i = blockIdx.x * 256 + threadIdx.x;
    if (i < *cnt) {
        const int row = list[i];
        out[row] = (int)(res0[row] & 0xFFFFFFFFull);
    }
}

// ---------------------------------------------------------------------------
// Fallback (round-4 verified): in-loop split, for small ws_size.
// ---------------------------------------------------------------------------
__global__ void prologue_fb(const float* __restrict__ E, float* __restrict__ esqb,
                            unsigned long long* __restrict__ packed) {
    const int t = blockIdx.x * 256 + threadIdx.x;
    if (t < N_ROWS) packed[t] = ~0ull;
    const int gw = t >> 6, lane = t & 63;
    const float4 v = ((const float4*)(E + (size_t)gw * D_DIM))[lane];
    float s = v.x * v.x + v.y * v.y + v.z * v.z + v.w * v.w;
#pragma unroll
    for (int off = 32; off; off >>= 1) s += __shfl_down(s, off, 64);
    if (lane == 0) esqb[gw] = s + 1024.0f;
}

__global__ __launch_bounds__(256, 2)
void vq_mfma_fallback(const float* __restrict__ X, const float* __restrict__ E,
                      const float* __restrict__ esqb,
                      unsigned long long* __restrict__ packed) {
    __shared__ uint4 fXh[128 * 8], fXl[128 * 8];
    __shared__ uint4 fEh[128 * 8], fEl[128 * 8];
    __shared__ float fEsq[2048];

    const int tid  = threadIdx.x;
    const int lane = tid & 63;
    const int wv   = tid >> 6;
    const int wr   = wv >> 1, wc = wv & 1;
    const int l31  = lane & 31;
    const int lh   = lane >> 5;
    const int row0 = blockIdx.x * 128;
    const int cs0  = blockIdx.y * 2048;

#pragma unroll
    for (int i = 0; i < 8; ++i) fEsq[tid + 256 * i] = esqb[cs0 + tid + 256 * i];

    const int sr = tid >> 3, sg = tid & 7;

    float best[2][16]; int bidx[2][16];
#pragma unroll
    for (int ti = 0; ti < 2; ++ti)
#pragma unroll
        for (int r = 0; r < 16; ++r) { best[ti][r] = 3.0e38f; bidx[ti][r] = 0; }

    f32x16 acc[2][2];

#pragma unroll 1
    for (int ct = 0; ct < 16; ++ct) {
#pragma unroll
        for (int ti = 0; ti < 2; ++ti)
#pragma unroll
            for (int tj = 0; tj < 2; ++tj)
#pragma unroll
                for (int i = 0; i < 16; ++i) acc[ti][tj][i] = 0.0f;

#pragma unroll 1
        for (int dc = 0; dc < 4; ++dc) {
            __syncthreads();
#pragma unroll
            for (int i = 0; i < 4; ++i) {
                const int r = 32 * i + sr;
                const float* p = X + (size_t)(row0 + r) * D_DIM + dc * 64 + sg * 8;
                const float4 a = *(const float4*)p, b = *(const float4*)(p + 4);
                uint4 hi, lo; cvt_granule(a, b, hi, lo);
                const int o = r * 8 + (sg ^ (r & 7));
                fXh[o] = hi; fXl[o] = lo;
            }
#pragma unroll
            for (int i = 0; i < 4; ++i) {
                const int r = 32 * i + sr;
                const float* p = E + (size_t)(cs0 + ct * 128 + r) * D_DIM + dc * 64 + sg * 8;
                const float4 a = *(const float4*)p, b = *(const float4*)(p + 4);
                uint4 hi, lo; cvt_granule(a, b, hi, lo);
                const int o = r * 8 + (sg ^ (r & 7));
                fEh[o] = hi; fEl[o] = lo;
            }
            __syncthreads();

#pragma unroll
            for (int s = 0; s < 4; ++s) {
                const int gi = s * 2 + lh;
                f16x8 axh[2], axl[2], beh[2], bel[2];
#pragma unroll
                for (int ti = 0; ti < 2; ++ti) {
                    const int r = wr * 64 + ti * 32 + l31;
                    const int o = r * 8 + (gi ^ (r & 7));
                    axh[ti] = __builtin_bit_cast(f16x8, fXh[o]);
                    axl[ti] = __builtin_bit_cast(f16x8, fXl[o]);
                }
#pragma unroll
                for (int tj = 0; tj < 2; ++tj) {
                    const int c = wc * 64 + tj * 32 + l31;
                    const int o = c * 8 + (gi ^ (c & 7));
                    beh[tj] = __builtin_bit_cast(f16x8, fEh[o]);
                    bel[tj] = __builtin_bit_cast(f16x8, fEl[o]);
                }
#pragma unroll
                for (int ti = 0; ti < 2; ++ti)
#pragma unroll
                    for (int tj = 0; tj < 2; ++tj) {
                        acc[ti][tj] = MFMA32(axl[ti], beh[tj], acc[ti][tj]);
                        acc[ti][tj] = MFMA32(axh[ti], bel[tj], acc[ti][tj]);
                        acc[ti][tj] = MFMA32(axh[ti], beh[tj], acc[ti][tj]);
                    }
            }
        }

#pragma unroll
        for (int tj = 0; tj < 2; ++tj) {
            const int cloc = ct * 128 + wc * 64 + tj * 32 + l31;
            const float eb = fEsq[cloc];
            const int  code = cs0 + cloc;
#pragma unroll
            for (int ti = 0; ti < 2; ++ti)
#pragma unroll
                for (int r = 0; r < 16; ++r) {
                    const float dv = fmaf(-2.0f, acc[ti][tj][r], eb);
                    if (dv < best[ti][r]) { best[ti][r] = dv; bidx[ti][r] = code; }
                }
        }
    }

#pragma unroll
    for (int ti = 0; ti < 2; ++ti)
#pragma unroll
        for (int r = 0; r < 16; ++r) {
            float b = best[ti][r]; int bi = bidx[ti][r];
#pragma unroll
            for (int m = 16; m >= 1; m >>= 1) {
                const float ov = __shfl_xor(b, m, 32);
                const int   oi = __shfl_xor(bi, m, 32);
                if (ov < b || (ov == b && oi < bi)) { b = ov; bi = oi; }
            }
            if (l31 == 0) {
                const int row = row0 + wr * 64 + ti * 32 + (r & 3) + 8 * (r >> 2) + 4 * lh;
                const unsigned long long p =
                    ((unsigned long long)__float_as_uint(b) << 32) | (unsigned)bi;
                atomicMin(&packed[row], p);
            }
        }
}

__global__ void finish_fb(const unsigned long long* __restrict__ packed,
                          int* __restrict__ out) {
    const int i = blockIdx.x * 256 + threadIdx.x;
    out[i] = (int)(unsigned)(packed[i] & 0xffffffffull);
}

// ---------------------------------------------------------------------------
extern "C" void kernel_launch(void* const* d_in, const int* in_sizes, int n_in,
                              void* d_out, int out_size, void* d_ws, size_t ws_size,
                              hipStream_t stream) {
    const float* X = (const float*)d_in[0];    // [32768, 256]
    const float* E = (const float*)d_in[1];    // [8192, 256]
    char* ws = (char*)d_ws;
    int* out = (int*)d_out;

    float* esqb = (float*)ws;                                         // 32 KB
    unsigned long long* res = (unsigned long long*)(ws + 32768);      // 512 KB (2 strips)
    float* res2 = (float*)(ws + 557056);                              // 256 KB
    int* cnt  = (int*)(ws + 819200);                                  // 16 B
    int* list = (int*)(ws + 819216);                                  // 128 KB
    const size_t base = 1048576;                                      // 1 MB
    const size_t szX  = (size_t)N_ROWS * D_DIM * 2;                   // 16 MB per half
    const size_t szE  = (size_t)K_CODES * D_DIM * 2;                  // 4 MB per half
    const size_t need = base + 2 * szX + 2 * szE;                     // ~41 MB

    if (ws_size >= need) {
        uint4* Xh = (uint4*)(ws + base);
        uint4* Xl = (uint4*)(ws + base + szX);
        uint4* Eh = (uint4*)(ws + base + 2 * szX);
        uint4* El = (uint4*)(ws + base + 2 * szX + szE);
        prep_kernel<<<dim3(3328), dim3(256), 0, stream>>>(X, E, Xh, Xl, Eh, El, esqb, cnt);
        vq_pass1<<<dim3(N_ROWS / BM, NSTRIP), dim3(256), 0, stream>>>(Xh, Eh, esqb, res, res2);
        merge_kernel<<<dim3(N_ROWS / 256), dim3(256), 0, stream>>>(res, res2, out, cnt, list);
        refine_kernel<<<dim3(1024, 8), dim3(256), 0, stream>>>(Xh, Xl, Eh, El, esqb,
                                                               cnt, list, res);
        finalize_kernel<<<dim3(N_ROWS / 256), dim3(256), 0, stream>>>(res, cnt, list, out);
    } else {
        unsigned long long* packed = (unsigned long long*)(ws + 32768);
        prologue_fb<<<dim3(2048), dim3(256), 0, stream>>>(E, esqb, packed);
        vq_mfma_fallback<<<dim3(N_ROWS / 128, 4), dim3(256), 0, stream>>>(X, E, esqb, packed);
        finish_fb<<<dim3(N_ROWS / 256), dim3(256), 0, stream>>>(packed, out);
    }
}

// Round 11
// 379.621 us; speedup vs baseline: 3.8575x; 1.0540x over previous
//
#include <hip/hip_runtime.h>

// N=32768 rows, K=8192 codes, D=256, fp32 in, int32 out.
constexpr int D_DIM   = 256;
constexpr int N_ROWS  = 32768;
constexpr int K_CODES = 8192;
// Quantized screen: dist*128 in key high bits. TQ/128 = 0.453 effective tau
// (round-10 verified tau=0.45 class; covers split error ~0.3 + quant 0.016).
constexpr unsigned TQ = 58;

typedef _Float16 f16x8  __attribute__((ext_vector_type(8)));
typedef __fp16   fp16x2 __attribute__((ext_vector_type(2)));
typedef float    f32x16 __attribute__((ext_vector_type(16)));

#define MFMA32(a, b, c) __builtin_amdgcn_mfma_f32_32x32x16_f16(a, b, c, 0, 0, 0)

// RTN split: hi = rn16(x), lo = rn16(x - hi).
__device__ __forceinline__ void cvt_rtn(const float4 a, const float4 b,
                                        uint4& hi, uint4& lo) {
    float f[8] = {a.x, a.y, a.z, a.w, b.x, b.y, b.z, b.w};
    unsigned hb[8], lb[8];
#pragma unroll
    for (int i = 0; i < 8; ++i) {
        _Float16 h = (_Float16)f[i];
        _Float16 l = (_Float16)(f[i] - (float)h);
        hb[i] = __builtin_bit_cast(unsigned short, h);
        lb[i] = __builtin_bit_cast(unsigned short, l);
    }
    hi = make_uint4(hb[0] | (hb[1] << 16), hb[2] | (hb[3] << 16),
                    hb[4] | (hb[5] << 16), hb[6] | (hb[7] << 16));
    lo = make_uint4(lb[0] | (lb[1] << 16), lb[2] | (lb[3] << 16),
                    lb[4] | (lb[5] << 16), lb[6] | (lb[7] << 16));
}

// RTZ split used by the (verified) fallback path.
__device__ __forceinline__ void cvt_granule(const float4 a, const float4 b,
                                            uint4& hi, uint4& lo) {
    fp16x2 h0 = __builtin_amdgcn_cvt_pkrtz(a.x, a.y);
    fp16x2 h1 = __builtin_amdgcn_cvt_pkrtz(a.z, a.w);
    fp16x2 h2 = __builtin_amdgcn_cvt_pkrtz(b.x, b.y);
    fp16x2 h3 = __builtin_amdgcn_cvt_pkrtz(b.z, b.w);
    fp16x2 l0 = __builtin_amdgcn_cvt_pkrtz(a.x - (float)h0.x, a.y - (float)h0.y);
    fp16x2 l1 = __builtin_amdgcn_cvt_pkrtz(a.z - (float)h1.x, a.w - (float)h1.y);
    fp16x2 l2 = __builtin_amdgcn_cvt_pkrtz(b.x - (float)h2.x, b.y - (float)h2.y);
    fp16x2 l3 = __builtin_amdgcn_cvt_pkrtz(b.z - (float)h3.x, b.w - (float)h3.y);
    hi = make_uint4(__builtin_bit_cast(unsigned, h0), __builtin_bit_cast(unsigned, h1),
                    __builtin_bit_cast(unsigned, h2), __builtin_bit_cast(unsigned, h3));
    lo = make_uint4(__builtin_bit_cast(unsigned, l0), __builtin_bit_cast(unsigned, l1),
                    __builtin_bit_cast(unsigned, l2), __builtin_bit_cast(unsigned, l3));
}

__device__ __forceinline__ void gl_lds16(const uint4* g, uint4* l) {
    __builtin_amdgcn_global_load_lds(
        (const __attribute__((address_space(1))) void*)g,
        (__attribute__((address_space(3))) void*)l, 16, 0, 0);
}

// ---------------------------------------------------------------------------
// Prep: RTN hi split of X, hi/lo split of E, esqb, counter zero.
//  X: g = rb*4096 + dc*1024 + L*128 + r   (rb: 128-row block, d = dc*64+L*8)
//  E: g = cb*8192 + dc*2048 + L*256 + c   (cb: 256-code tile)
// ---------------------------------------------------------------------------
__global__ __launch_bounds__(256)
void prep_kernel(const float* __restrict__ X, const float* __restrict__ E,
                 uint4* __restrict__ Xh,
                 uint4* __restrict__ Eh, uint4* __restrict__ El,
                 float* __restrict__ esqb, int* __restrict__ cnt) {
    const int tid = threadIdx.x, bid = blockIdx.x;
    if (bid < 1024) {
#pragma unroll 1
        for (int it = 0; it < 4; ++it) {
            const int gid = bid * 1024 + it * 256 + tid;
            const int rb = gid >> 12, rem = gid & 4095;
            const int dc = rem >> 10, L = (rem >> 7) & 7, r = rem & 127;
            const float* p = X + (size_t)(rb * 128 + r) * D_DIM + dc * 64 + L * 8;
            const float4 a = *(const float4*)p, b = *(const float4*)(p + 4);
            uint4 hi, lo; cvt_rtn(a, b, hi, lo);
            Xh[gid] = hi;
        }
    } else if (bid < 1280) {
#pragma unroll 1
        for (int it = 0; it < 4; ++it) {
            const int gid = (bid - 1024) * 1024 + it * 256 + tid;
            const int cb = gid >> 13, rem = gid & 8191;
            const int dc = rem >> 11, L = (rem >> 8) & 7, c = rem & 255;
            const float* p = E + (size_t)(cb * 256 + c) * D_DIM + dc * 64 + L * 8;
            const float4 a = *(const float4*)p, b = *(const float4*)(p + 4);
            uint4 hi, lo; cvt_rtn(a, b, hi, lo);
            Eh[gid] = hi; El[gid] = lo;
        }
    } else {
        if (bid == 1280 && tid == 0) *cnt = 0;
        const int t = (bid - 1280) * 256 + tid;
        const int gw = t >> 6, lane = t & 63;
        const float4 v = ((const float4*)(E + (size_t)gw * D_DIM))[lane];
        float s = v.x * v.x + v.y * v.y + v.z * v.z + v.w * v.w;
#pragma unroll
        for (int off = 32; off; off >>= 1) s += __shfl_down(s, off, 64);
        if (lane == 0) esqb[gw] = s + 1024.0f;
    }
}

// ---------------------------------------------------------------------------
// Pass 1: 1-product (xh*eh) screen, quantized-key top-2 (pure u32 lattice).
// key = ((unsigned)(dist*128) << 13) | code. Block 128 rows x 2048-code strip
// (4 strips); wave (wr,wc) owns 64x64 = 2x2 MFMA tiles. State: 32 cells x
// (best,best2) u32 = 64 VGPR; acc 64 AGPR -> 3 waves/SIMD, 3 blocks/CU.
// ---------------------------------------------------------------------------
__global__ __launch_bounds__(256, 3)
void vq_pass1(const uint4* __restrict__ Xh, const uint4* __restrict__ Eh,
              const float* __restrict__ esqb, uint2* __restrict__ res) {
    __shared__ uint4 sXh[1024];      // [L(8)][r(128)], 16 KB
    __shared__ uint4 sEh[1024];      // [L(8)][c(128)], 16 KB
    __shared__ uint2 slot[2][128];   // [wc][row], 1 KB

    const int tid  = threadIdx.x;
    const int lane = tid & 63, wv = tid >> 6, wr = wv >> 1, wc = wv & 1;
    const int l31  = lane & 31, lh = lane >> 5;
    const int wbase = wv << 6;
    const int bx = blockIdx.x, strip = blockIdx.y;
    const int cs0 = strip * 2048;

    const uint4* Xhb = Xh + bx * 4096;

    unsigned best[2][16], best2[2][16];
#pragma unroll
    for (int ti = 0; ti < 2; ++ti)
#pragma unroll
        for (int r = 0; r < 16; ++r) { best[ti][r] = 0xFFFFFFFFu; best2[ti][r] = 0xFFFFFFFFu; }

    f32x16 acc[2][2];

#pragma unroll 1
    for (int ct = 0; ct < 16; ++ct) {                 // 128-code tiles
        const int cb   = strip * 8 + (ct >> 1);       // 256-code block in E layout
        const int coff = (ct & 1) * 128;
        const uint4* Ehb = Eh + (size_t)cb * 8192;

#pragma unroll
        for (int ti = 0; ti < 2; ++ti)
#pragma unroll
            for (int tj = 0; tj < 2; ++tj)
#pragma unroll
                for (int i = 0; i < 16; ++i) acc[ti][tj][i] = 0.0f;

#pragma unroll 1
        for (int dc = 0; dc < 4; ++dc) {
            __syncthreads();
            // X chunk: 1024 granules, 4 loads/wave
#pragma unroll
            for (int i = 0; i < 4; ++i)
                gl_lds16(Xhb + dc * 1024 + i * 256 + tid, &sXh[i * 256 + wbase]);
            // E chunk: 128 codes x 8 L; load idx = wv*4+i -> (L, code-half)
#pragma unroll
            for (int i = 0; i < 4; ++i) {
                const int idx = wv * 4 + i, L = idx >> 1, ch = idx & 1;
                gl_lds16(Ehb + dc * 2048 + L * 256 + coff + ch * 64 + lane,
                         &sEh[L * 128 + ch * 64]);
            }
            __syncthreads();

#pragma unroll
            for (int s = 0; s < 4; ++s) {
                const int L = s * 2 + lh;
                f16x8 a0[2], b0[2];
#pragma unroll
                for (int ti = 0; ti < 2; ++ti)
                    a0[ti] = __builtin_bit_cast(f16x8, sXh[L * 128 + wr * 64 + ti * 32 + l31]);
#pragma unroll
                for (int tj = 0; tj < 2; ++tj)
                    b0[tj] = __builtin_bit_cast(f16x8, sEh[L * 128 + wc * 64 + tj * 32 + l31]);
#pragma unroll
                for (int ti = 0; ti < 2; ++ti)
#pragma unroll
                    for (int tj = 0; tj < 2; ++tj)
                        acc[ti][tj] = MFMA32(a0[ti], b0[tj], acc[ti][tj]);
            }
        }

        // epilogue: keyed top-2 lattice update (6 VALU/cell, order-free)
#pragma unroll
        for (int tj = 0; tj < 2; ++tj) {
            const int code = cs0 + ct * 128 + wc * 64 + tj * 32 + l31;
            const float eb128 = esqb[code] * 128.0f;      // (e_sq+1024)*128
#pragma unroll
            for (int ti = 0; ti < 2; ++ti)
#pragma unroll
                for (int r = 0; r < 16; ++r) {
                    const float dq = fmaf(-256.0f, acc[ti][tj][r], eb128);
                    const unsigned q   = (unsigned)dq;          // < 2^19
                    const unsigned key = (q << 13) + (unsigned)code;
                    const unsigned t   = key > best[ti][r] ? key : best[ti][r];
                    best2[ti][r] = best2[ti][r] < t ? best2[ti][r] : t;
                    best[ti][r]  = best[ti][r] < key ? best[ti][r] : key;
                }
        }
    }

    // butterfly over 32 code-lanes (exact top-2 merge, u32)
#pragma unroll
    for (int ti = 0; ti < 2; ++ti)
#pragma unroll
        for (int r = 0; r < 16; ++r) {
            unsigned b1 = best[ti][r], b2 = best2[ti][r];
#pragma unroll
            for (int m = 16; m >= 1; m >>= 1) {
                const unsigned o1 = (unsigned)__shfl_xor((int)b1, m, 32);
                const unsigned o2 = (unsigned)__shfl_xor((int)b2, m, 32);
                const unsigned t  = b1 > o1 ? b1 : o1;
                b1 = b1 < o1 ? b1 : o1;
                const unsigned m2 = b2 < o2 ? b2 : o2;
                b2 = m2 < t ? m2 : t;
            }
            if (l31 == 0) {
                const int row = wr * 64 + ti * 32 + (r & 3) + 8 * (r >> 2) + 4 * lh;
                slot[wc][row] = make_uint2(b1, b2);
            }
        }

    __syncthreads();
    if (tid < 128) {
        const uint2 A = slot[0][tid], B = slot[1][tid];
        const unsigned t  = A.x > B.x ? A.x : B.x;
        const unsigned b1 = A.x < B.x ? A.x : B.x;
        const unsigned m2 = A.y < B.y ? A.y : B.y;
        const unsigned b2 = m2 < t ? m2 : t;
        res[(size_t)strip * N_ROWS + bx * 128 + tid] = make_uint2(b1, b2);
    }
}

// ---------------------------------------------------------------------------
// Merge 4 strips (exact keyed top-2): clean rows -> out; ambiguous -> list.
// ---------------------------------------------------------------------------
__global__ void merge_kernel(const uint2* __restrict__ res,
                             unsigned long long* __restrict__ res0,
                             int* __restrict__ out,
                             int* __restrict__ cnt, int* __restrict__ list) {
    const int row = blockIdx.x * 256 + threadIdx.x;
    unsigned b1 = 0xFFFFFFFFu, b2 = 0xFFFFFFFFu;
#pragma unroll
    for (int s = 0; s < 4; ++s) {
        const uint2 v = res[(size_t)s * N_ROWS + row];
        const unsigned t = b1 > v.x ? b1 : v.x;
        b1 = b1 < v.x ? b1 : v.x;
        const unsigned m2 = b2 < v.y ? b2 : v.y;
        b2 = m2 < t ? m2 : t;
    }
    out[row] = (int)(b1 & 8191u);
    if ((b2 >> 13) - (b1 >> 13) < TQ) {
        const int p = atomicAdd(cnt, 1);
        list[p] = row;
        res0[row] = ~0ull;
    }
}

// ---------------------------------------------------------------------------
// Refine: flagged rows, exact 3-product over all codes (verified structure).
// Block = 32 gathered rows x 1024-code strip (grid 1024 x 8, uniform exit).
// A rows converted from raw fp32 on the fly (same RTN split as prep).
// ---------------------------------------------------------------------------
__global__ __launch_bounds__(256, 1)
void refine_kernel(const float* __restrict__ X,
                   const uint4* __restrict__ Eh, const uint4* __restrict__ El,
                   const float* __restrict__ esqb, const int* __restrict__ cnt,
                   const int* __restrict__ list, unsigned long long* __restrict__ res0) {
    __shared__ int  rows_s[32];
    __shared__ uint4 sAh[1024], sAl[1024];   // 32 KB

    const int n = *cnt;
    const int base = blockIdx.x * 32;
    if (base >= n) return;                   // block-uniform
    const int tid = threadIdx.x;
    if (tid < 32) { const int j = base + tid; rows_s[tid] = list[j < n ? j : base]; }
    __syncthreads();

    // gather + split A: granule slot Lg (0..31) x row slot rr (0..31)
#pragma unroll
    for (int jj = 0; jj < 4; ++jj) {
        const int gg = jj * 256 + tid, Lg = gg >> 5, rr = gg & 31;
        const int row = rows_s[rr];
        const float* p = X + (size_t)row * D_DIM + Lg * 8;
        const float4 a = *(const float4*)p, b = *(const float4*)(p + 4);
        uint4 hi, lo; cvt_rtn(a, b, hi, lo);
        sAh[Lg * 32 + rr] = hi; sAl[Lg * 32 + rr] = lo;
    }
    __syncthreads();

    const int lane = tid & 63, wv = tid >> 6, l31 = lane & 31, lh = lane >> 5;
    const int cbase = blockIdx.y * 1024 + wv * 256;

    float bestv[16]; int besti[16];
#pragma unroll
    for (int r = 0; r < 16; ++r) { bestv[r] = 3.0e38f; besti[r] = 0; }

#pragma unroll 1
    for (int ps = 0; ps < 2; ++ps) {         // 2 passes of 128 codes
        const int c0 = cbase + ps * 128;
        f32x16 acc[4];
#pragma unroll
        for (int tj = 0; tj < 4; ++tj)
#pragma unroll
            for (int i = 0; i < 16; ++i) acc[tj][i] = 0.0f;

#pragma unroll
        for (int ks = 0; ks < 16; ++ks) {
            const int Lg = ks * 2 + lh;
            f16x8 b0[4], b1[4];
#pragma unroll
            for (int tj = 0; tj < 4; ++tj) {
                const int c = c0 + tj * 32 + l31;
                const int eg = (c >> 8) * 8192 + (Lg >> 3) * 2048 + (Lg & 7) * 256 + (c & 255);
                b0[tj] = __builtin_bit_cast(f16x8, Eh[eg]);
                b1[tj] = __builtin_bit_cast(f16x8, El[eg]);
            }
            const f16x8 a0 = __builtin_bit_cast(f16x8, sAh[Lg * 32 + l31]);
            const f16x8 a1 = __builtin_bit_cast(f16x8, sAl[Lg * 32 + l31]);
#pragma unroll
            for (int tj = 0; tj < 4; ++tj) acc[tj] = MFMA32(a1, b0[tj], acc[tj]);
#pragma unroll
            for (int tj = 0; tj < 4; ++tj) acc[tj] = MFMA32(a0, b1[tj], acc[tj]);
#pragma unroll
            for (int tj = 0; tj < 4; ++tj) acc[tj] = MFMA32(a0, b0[tj], acc[tj]);
        }

#pragma unroll
        for (int tj = 0; tj < 4; ++tj) {
            const int c = c0 + tj * 32 + l31;
            const float eb = esqb[c];
#pragma unroll
            for (int r = 0; r < 16; ++r) {
                const float dv = fmaf(-2.0f, acc[tj][r], eb);
                if (dv < bestv[r]) { bestv[r] = dv; besti[r] = c; }
            }
        }
    }

#pragma unroll
    for (int r = 0; r < 16; ++r) {
        float v = bestv[r]; int bi = besti[r];
#pragma unroll
        for (int m = 16; m >= 1; m >>= 1) {
            const float ov = __shfl_xor(v, m, 32);
            const int   oi = __shfl_xor(bi, m, 32);
            if (ov < v || (ov == v && oi < bi)) { v = ov; bi = oi; }
        }
        if (l31 == 0) {
            const int rl = (r & 3) + 8 * (r >> 2) + 4 * lh;   // 0..31
            atomicMin(&res0[rows_s[rl]],
                      ((unsigned long long)__float_as_uint(v) << 32) | (unsigned)bi);
        }
    }
}

// ---------------------------------------------------------------------------
__global__ void finalize_kernel(const unsigned long long* __restrict__ res0,
                                const int* __restrict__ cnt, const int* __restrict__ list,
                                int* __restrict__ out) {
    const int i = blockIdx.x * 256 + threadIdx.x;
    if (i < *cnt) {
        const int row = list[i];
        out[row] = (int)(res0[row] & 0xFFFFFFFFull);
    }
}

// ---------------------------------------------------------------------------
// Fallback (round-4 verified): in-loop split, for small ws_size.
// ---------------------------------------------------------------------------
__global__ void prologue_fb(const float* __restrict__ E, float* __restrict__ esqb,
                            unsigned long long* __restrict__ packed) {
    const int t = blockIdx.x * 256 + threadIdx.x;
    if (t < N_ROWS) packed[t] = ~0ull;
    const int gw = t >> 6, lane = t & 63;
    const float4 v = ((const float4*)(E + (size_t)gw * D_DIM))[lane];
    float s = v.x * v.x + v.y * v.y + v.z * v.z + v.w * v.w;
#pragma unroll
    for (int off = 32; off; off >>= 1) s += __shfl_down(s, off, 64);
    if (lane == 0) esqb[gw] = s + 1024.0f;
}

__global__ __launch_bounds__(256, 2)
void vq_mfma_fallback(const float* __restrict__ X, const float* __restrict__ E,
                      const float* __restrict__ esqb,
                      unsigned long long* __restrict__ packed) {
    __shared__ uint4 fXh[128 * 8], fXl[128 * 8];
    __shared__ uint4 fEh[128 * 8], fEl[128 * 8];
    __shared__ float fEsq[2048];

    const int tid  = threadIdx.x;
    const int lane = tid & 63;
    const int wv   = tid >> 6;
    const int wr   = wv >> 1, wc = wv & 1;
    const int l31  = lane & 31;
    const int lh   = lane >> 5;
    const int row0 = blockIdx.x * 128;
    const int cs0  = blockIdx.y * 2048;

#pragma unroll
    for (int i = 0; i < 8; ++i) fEsq[tid + 256 * i] = esqb[cs0 + tid + 256 * i];

    const int sr = tid >> 3, sg = tid & 7;

    float best[2][16]; int bidx[2][16];
#pragma unroll
    for (int ti = 0; ti < 2; ++ti)
#pragma unroll
        for (int r = 0; r < 16; ++r) { best[ti][r] = 3.0e38f; bidx[ti][r] = 0; }

    f32x16 acc[2][2];

#pragma unroll 1
    for (int ct = 0; ct < 16; ++ct) {
#pragma unroll
        for (int ti = 0; ti < 2; ++ti)
#pragma unroll
            for (int tj = 0; tj < 2; ++tj)
#pragma unroll
                for (int i = 0; i < 16; ++i) acc[ti][tj][i] = 0.0f;

#pragma unroll 1
        for (int dc = 0; dc < 4; ++dc) {
            __syncthreads();
#pragma unroll
            for (int i = 0; i < 4; ++i) {
                const int r = 32 * i + sr;
                const float* p = X + (size_t)(row0 + r) * D_DIM + dc * 64 + sg * 8;
                const float4 a = *(const float4*)p, b = *(const float4*)(p + 4);
                uint4 hi, lo; cvt_granule(a, b, hi, lo);
                const int o = r * 8 + (sg ^ (r & 7));
                fXh[o] = hi; fXl[o] = lo;
            }
#pragma unroll
            for (int i = 0; i < 4; ++i) {
                const int r = 32 * i + sr;
                const float* p = E + (size_t)(cs0 + ct * 128 + r) * D_DIM + dc * 64 + sg * 8;
                const float4 a = *(const float4*)p, b = *(const float4*)(p + 4);
                uint4 hi, lo; cvt_granule(a, b, hi, lo);
                const int o = r * 8 + (sg ^ (r & 7));
                fEh[o] = hi; fEl[o] = lo;
            }
            __syncthreads();

#pragma unroll
            for (int s = 0; s < 4; ++s) {
                const int gi = s * 2 + lh;
                f16x8 axh[2], axl[2], beh[2], bel[2];
#pragma unroll
                for (int ti = 0; ti < 2; ++ti) {
                    const int r = wr * 64 + ti * 32 + l31;
                    const int o = r * 8 + (gi ^ (r & 7));
                    axh[ti] = __builtin_bit_cast(f16x8, fXh[o]);
                    axl[ti] = __builtin_bit_cast(f16x8, fXl[o]);
                }
#pragma unroll
                for (int tj = 0; tj < 2; ++tj) {
                    const int c = wc * 64 + tj * 32 + l31;
                    const int o = c * 8 + (gi ^ (c & 7));
                    beh[tj] = __builtin_bit_cast(f16x8, fEh[o]);
                    bel[tj] = __builtin_bit_cast(f16x8, fEl[o]);
                }
#pragma unroll
                for (int ti = 0; ti < 2; ++ti)
#pragma unroll
                    for (int tj = 0; tj < 2; ++tj) {
                        acc[ti][tj] = MFMA32(axl[ti], beh[tj], acc[ti][tj]);
                        acc[ti][tj] = MFMA32(axh[ti], bel[tj], acc[ti][tj]);
                        acc[ti][tj] = MFMA32(axh[ti], beh[tj], acc[ti][tj]);
                    }
            }
        }

#pragma unroll
        for (int tj = 0; tj < 2; ++tj) {
            const int cloc = ct * 128 + wc * 64 + tj * 32 + l31;
            const float eb = fEsq[cloc];
            const int  code = cs0 + cloc;
#pragma unroll
            for (int ti = 0; ti < 2; ++ti)
#pragma unroll
                for (int r = 0; r < 16; ++r) {
                    const float dv = fmaf(-2.0f, acc[ti][tj][r], eb);
                    if (dv < best[ti][r]) { best[ti][r] = dv; bidx[ti][r] = code; }
                }
        }
    }

#pragma unroll
    for (int ti = 0; ti < 2; ++ti)
#pragma unroll
        for (int r = 0; r < 16; ++r) {
            float b = best[ti][r]; int bi = bidx[ti][r];
#pragma unroll
            for (int m = 16; m >= 1; m >>= 1) {
                const float ov = __shfl_xor(b, m, 32);
                const int   oi = __shfl_xor(bi, m, 32);
                if (ov < b || (ov == b && oi < bi)) { b = ov; bi = oi; }
            }
            if (l31 == 0) {
                const int row = row0 + wr * 64 + ti * 32 + (r & 3) + 8 * (r >> 2) + 4 * lh;
                const unsigned long long p =
                    ((unsigned long long)__float_as_uint(b) << 32) | (unsigned)bi;
                atomicMin(&packed[row], p);
            }
        }
}

__global__ void finish_fb(const unsigned long long* __restrict__ packed,
                          int* __restrict__ out) {
    const int i = blockIdx.x * 256 + threadIdx.x;
    out[i] = (int)(unsigned)(packed[i] & 0xffffffffull);
}

// ---------------------------------------------------------------------------
extern "C" void kernel_launch(void* const* d_in, const int* in_sizes, int n_in,
                              void* d_out, int out_size, void* d_ws, size_t ws_size,
                              hipStream_t stream) {
    const float* X = (const float*)d_in[0];    // [32768, 256]
    const float* E = (const float*)d_in[1];    // [8192, 256]
    char* ws = (char*)d_ws;
    int* out = (int*)d_out;

    float* esqb = (float*)ws;                                    // 32 KB @ 0
    uint2* res  = (uint2*)(ws + 32768);                          // 1 MB (4 strips)
    unsigned long long* res0 = (unsigned long long*)(ws + 1081344); // 256 KB
    int* cnt  = (int*)(ws + 1343488);                            // 16 B
    int* list = (int*)(ws + 1343504);                            // 128 KB
    const size_t base = 1572864;                                 // 1.5 MB
    const size_t szX  = (size_t)N_ROWS * D_DIM * 2;              // 16 MB (hi only)
    const size_t szE  = (size_t)K_CODES * D_DIM * 2;             // 4 MB per half
    const size_t need = base + szX + 2 * szE;                    // ~25.5 MB

    if (ws_size >= need) {
        uint4* Xh = (uint4*)(ws + base);
        uint4* Eh = (uint4*)(ws + base + szX);
        uint4* El = (uint4*)(ws + base + szX + szE);
        prep_kernel<<<dim3(3328), dim3(256), 0, stream>>>(X, E, Xh, Eh, El, esqb, cnt);
        vq_pass1<<<dim3(N_ROWS / 128, 4), dim3(256), 0, stream>>>(Xh, Eh, esqb, res);
        merge_kernel<<<dim3(N_ROWS / 256), dim3(256), 0, stream>>>(res, res0, out, cnt, list);
        refine_kernel<<<dim3(1024, 8), dim3(256), 0, stream>>>(X, Eh, El, esqb,
                                                               cnt, list, res0);
        finalize_kernel<<<dim3(N_ROWS / 256), dim3(256), 0, stream>>>(res0, cnt, list, out);
    } else {
        unsigned long long* packed = (unsigned long long*)(ws + 32768);
        prologue_fb<<<dim3(2048), dim3(256), 0, stream>>>(E, esqb, packed);
        vq_mfma_fallback<<<dim3(N_ROWS / 128, 4), dim3(256), 0, stream>>>(X, E, esqb, packed);
        finish_fb<<<dim3(N_ROWS / 256), dim3(256), 0, stream>>>(packed, out);
    }
}

// Round 12
// 361.930 us; speedup vs baseline: 4.0461x; 1.0489x over previous
//
#include <hip/hip_runtime.h>

// N=32768 rows, K=8192 codes, D=256, fp32 in, int32 out.
constexpr int D_DIM   = 256;
constexpr int N_ROWS  = 32768;
constexpr int K_CODES = 8192;
// Quantized screen: dist*128 in key high bits. TQ/128 = 0.453 effective tau
// (round-10 verified tau=0.45 class; covers split error ~0.3 + quant 0.016).
constexpr unsigned TQ = 58;

typedef _Float16 f16x8  __attribute__((ext_vector_type(8)));
typedef __fp16   fp16x2 __attribute__((ext_vector_type(2)));
typedef float    f32x16 __attribute__((ext_vector_type(16)));

#define MFMA32(a, b, c) __builtin_amdgcn_mfma_f32_32x32x16_f16(a, b, c, 0, 0, 0)

// RTN split: hi = rn16(x), lo = rn16(x - hi).
__device__ __forceinline__ void cvt_rtn(const float4 a, const float4 b,
                                        uint4& hi, uint4& lo) {
    float f[8] = {a.x, a.y, a.z, a.w, b.x, b.y, b.z, b.w};
    unsigned hb[8], lb[8];
#pragma unroll
    for (int i = 0; i < 8; ++i) {
        _Float16 h = (_Float16)f[i];
        _Float16 l = (_Float16)(f[i] - (float)h);
        hb[i] = __builtin_bit_cast(unsigned short, h);
        lb[i] = __builtin_bit_cast(unsigned short, l);
    }
    hi = make_uint4(hb[0] | (hb[1] << 16), hb[2] | (hb[3] << 16),
                    hb[4] | (hb[5] << 16), hb[6] | (hb[7] << 16));
    lo = make_uint4(lb[0] | (lb[1] << 16), lb[2] | (lb[3] << 16),
                    lb[4] | (lb[5] << 16), lb[6] | (lb[7] << 16));
}

// RTZ split used by the (verified) fallback path.
__device__ __forceinline__ void cvt_granule(const float4 a, const float4 b,
                                            uint4& hi, uint4& lo) {
    fp16x2 h0 = __builtin_amdgcn_cvt_pkrtz(a.x, a.y);
    fp16x2 h1 = __builtin_amdgcn_cvt_pkrtz(a.z, a.w);
    fp16x2 h2 = __builtin_amdgcn_cvt_pkrtz(b.x, b.y);
    fp16x2 h3 = __builtin_amdgcn_cvt_pkrtz(b.z, b.w);
    fp16x2 l0 = __builtin_amdgcn_cvt_pkrtz(a.x - (float)h0.x, a.y - (float)h0.y);
    fp16x2 l1 = __builtin_amdgcn_cvt_pkrtz(a.z - (float)h1.x, a.w - (float)h1.y);
    fp16x2 l2 = __builtin_amdgcn_cvt_pkrtz(b.x - (float)h2.x, b.y - (float)h2.y);
    fp16x2 l3 = __builtin_amdgcn_cvt_pkrtz(b.z - (float)h3.x, b.w - (float)h3.y);
    hi = make_uint4(__builtin_bit_cast(unsigned, h0), __builtin_bit_cast(unsigned, h1),
                    __builtin_bit_cast(unsigned, h2), __builtin_bit_cast(unsigned, h3));
    lo = make_uint4(__builtin_bit_cast(unsigned, l0), __builtin_bit_cast(unsigned, l1),
                    __builtin_bit_cast(unsigned, l2), __builtin_bit_cast(unsigned, l3));
}

__device__ __forceinline__ void gl_lds16(const uint4* g, uint4* l) {
    __builtin_amdgcn_global_load_lds(
        (const __attribute__((address_space(1))) void*)g,
        (__attribute__((address_space(3))) void*)l, 16, 0, 0);
}

// ---------------------------------------------------------------------------
// Prep: RTN hi split of X, hi/lo split of E, esqb, counter zero.
//  X: g = rb*4096 + Lg*128 + r   (rb: 128-row block, Lg = d/8 layer 0..31)
//  E: g = cb*8192 + Lg*256 + c   (cb: 256-code tile)
// ---------------------------------------------------------------------------
__global__ __launch_bounds__(256)
void prep_kernel(const float* __restrict__ X, const float* __restrict__ E,
                 uint4* __restrict__ Xh,
                 uint4* __restrict__ Eh, uint4* __restrict__ El,
                 float* __restrict__ esqb, int* __restrict__ cnt) {
    const int tid = threadIdx.x, bid = blockIdx.x;
    if (bid < 1024) {
#pragma unroll 1
        for (int it = 0; it < 4; ++it) {
            const int gid = bid * 1024 + it * 256 + tid;
            const int rb = gid >> 12, rem = gid & 4095;
            const int Lg = rem >> 7, r = rem & 127;
            const float* p = X + (size_t)(rb * 128 + r) * D_DIM + Lg * 8;
            const float4 a = *(const float4*)p, b = *(const float4*)(p + 4);
            uint4 hi, lo; cvt_rtn(a, b, hi, lo);
            Xh[gid] = hi;
        }
    } else if (bid < 1280) {
#pragma unroll 1
        for (int it = 0; it < 4; ++it) {
            const int gid = (bid - 1024) * 1024 + it * 256 + tid;
            const int cb = gid >> 13, rem = gid & 8191;
            const int Lg = rem >> 8, c = rem & 255;
            const float* p = E + (size_t)(cb * 256 + c) * D_DIM + Lg * 8;
            const float4 a = *(const float4*)p, b = *(const float4*)(p + 4);
            uint4 hi, lo; cvt_rtn(a, b, hi, lo);
            Eh[gid] = hi; El[gid] = lo;
        }
    } else {
        if (bid == 1280 && tid == 0) *cnt = 0;
        const int t = (bid - 1280) * 256 + tid;
        const int gw = t >> 6, lane = t & 63;
        const float4 v = ((const float4*)(E + (size_t)gw * D_DIM))[lane];
        float s = v.x * v.x + v.y * v.y + v.z * v.z + v.w * v.w;
#pragma unroll
        for (int off = 32; off; off >>= 1) s += __shfl_down(s, off, 64);
        if (lane == 0) esqb[gw] = s + 1024.0f;
    }
}

// ---------------------------------------------------------------------------
// Pass 1: 1-product (xh*eh) screen, quantized-key top-2 (pure u32 lattice).
// X block (128 rows x 256 d hi, 64 KB) staged to LDS ONCE; E fragments loaded
// DIRECTLY global->VGPR (blocked layout: lane-contiguous 16 B, coalesced,
// L2-resident strip). NO barriers in the main loop -> compiler pipelines the
// B-loads with fine-grained vmcnt across K-steps (AITER pattern). K-step
// order and epilogue identical to the round-11-verified kernel.
// ---------------------------------------------------------------------------
__global__ __launch_bounds__(256, 2)
void vq_pass1(const uint4* __restrict__ Xh, const uint4* __restrict__ Eh,
              const float* __restrict__ esqb, uint2* __restrict__ res) {
    __shared__ uint4 sXh[4096];      // [Lg(32)][r(128)], 64 KB
    __shared__ uint2 slot[2][128];   // [wc][row], 1 KB

    const int tid  = threadIdx.x;
    const int lane = tid & 63, wv = tid >> 6, wr = wv >> 1, wc = wv & 1;
    const int l31  = lane & 31, lh = lane >> 5;
    const int wbase = wv << 6;
    const int bx = blockIdx.x, strip = blockIdx.y;
    const int cs0 = strip * 2048;

    const uint4* Xhb = Xh + bx * 4096;

    // ---- stage X hi (whole 256-d) once ----
#pragma unroll
    for (int i = 0; i < 16; ++i)
        gl_lds16(Xhb + i * 256 + tid, &sXh[i * 256 + wbase]);
    __syncthreads();

    unsigned best[2][16], best2[2][16];
#pragma unroll
    for (int ti = 0; ti < 2; ++ti)
#pragma unroll
        for (int r = 0; r < 16; ++r) { best[ti][r] = 0xFFFFFFFFu; best2[ti][r] = 0xFFFFFFFFu; }

    f32x16 acc[2][2];
    const int arow = wr * 64 + l31;          // A-frag row base (ti adds 32)

#pragma unroll 1
    for (int ct = 0; ct < 16; ++ct) {        // 128-code tiles
        // E base for this wave's 64-code column (lane-contiguous granules)
        const uint4* __restrict__ Eb =
            Eh + (size_t)(strip * 8 + (ct >> 1)) * 8192 + (ct & 1) * 128 + wc * 64 + l31;

#pragma unroll
        for (int ti = 0; ti < 2; ++ti)
#pragma unroll
            for (int tj = 0; tj < 2; ++tj)
#pragma unroll
                for (int i = 0; i < 16; ++i) acc[ti][tj][i] = 0.0f;

#pragma unroll 4
        for (int k = 0; k < 16; ++k) {       // K-steps of 16 dims, barrier-free
            const int Lg = k * 2 + lh;
            const f16x8 b0 = __builtin_bit_cast(f16x8, Eb[Lg * 256]);
            const f16x8 b1 = __builtin_bit_cast(f16x8, Eb[Lg * 256 + 32]);
            const f16x8 a0 = __builtin_bit_cast(f16x8, sXh[Lg * 128 + arow]);
            const f16x8 a1 = __builtin_bit_cast(f16x8, sXh[Lg * 128 + arow + 32]);
            acc[0][0] = MFMA32(a0, b0, acc[0][0]);
            acc[0][1] = MFMA32(a0, b1, acc[0][1]);
            acc[1][0] = MFMA32(a1, b0, acc[1][0]);
            acc[1][1] = MFMA32(a1, b1, acc[1][1]);
        }

        // epilogue: keyed top-2 lattice update (order-free)
#pragma unroll
        for (int tj = 0; tj < 2; ++tj) {
            const int code = cs0 + ct * 128 + wc * 64 + tj * 32 + l31;
            const float eb128 = esqb[code] * 128.0f;      // (e_sq+1024)*128
#pragma unroll
            for (int ti = 0; ti < 2; ++ti)
#pragma unroll
                for (int r = 0; r < 16; ++r) {
                    const float dq = fmaf(-256.0f, acc[ti][tj][r], eb128);
                    const unsigned q   = (unsigned)dq;          // < 2^19
                    const unsigned key = (q << 13) + (unsigned)code;
                    const unsigned t   = key > best[ti][r] ? key : best[ti][r];
                    best2[ti][r] = best2[ti][r] < t ? best2[ti][r] : t;
                    best[ti][r]  = best[ti][r] < key ? best[ti][r] : key;
                }
        }
    }

    // butterfly over 32 code-lanes (exact top-2 merge, u32)
#pragma unroll
    for (int ti = 0; ti < 2; ++ti)
#pragma unroll
        for (int r = 0; r < 16; ++r) {
            unsigned b1 = best[ti][r], b2 = best2[ti][r];
#pragma unroll
            for (int m = 16; m >= 1; m >>= 1) {
                const unsigned o1 = (unsigned)__shfl_xor((int)b1, m, 32);
                const unsigned o2 = (unsigned)__shfl_xor((int)b2, m, 32);
                const unsigned t  = b1 > o1 ? b1 : o1;
                b1 = b1 < o1 ? b1 : o1;
                const unsigned m2 = b2 < o2 ? b2 : o2;
                b2 = m2 < t ? m2 : t;
            }
            if (l31 == 0) {
                const int row = wr * 64 + ti * 32 + (r & 3) + 8 * (r >> 2) + 4 * lh;
                slot[wc][row] = make_uint2(b1, b2);
            }
        }

    __syncthreads();
    if (tid < 128) {
        const uint2 A = slot[0][tid], B = slot[1][tid];
        const unsigned t  = A.x > B.x ? A.x : B.x;
        const unsigned b1 = A.x < B.x ? A.x : B.x;
        const unsigned m2 = A.y < B.y ? A.y : B.y;
        const unsigned b2 = m2 < t ? m2 : t;
        res[(size_t)strip * N_ROWS + bx * 128 + tid] = make_uint2(b1, b2);
    }
}

// ---------------------------------------------------------------------------
// Merge 4 strips (exact keyed top-2): clean rows -> out; ambiguous -> list.
// ---------------------------------------------------------------------------
__global__ void merge_kernel(const uint2* __restrict__ res,
                             unsigned long long* __restrict__ res0,
                             int* __restrict__ out,
                             int* __restrict__ cnt, int* __restrict__ list) {
    const int row = blockIdx.x * 256 + threadIdx.x;
    unsigned b1 = 0xFFFFFFFFu, b2 = 0xFFFFFFFFu;
#pragma unroll
    for (int s = 0; s < 4; ++s) {
        const uint2 v = res[(size_t)s * N_ROWS + row];
        const unsigned t = b1 > v.x ? b1 : v.x;
        b1 = b1 < v.x ? b1 : v.x;
        const unsigned m2 = b2 < v.y ? b2 : v.y;
        b2 = m2 < t ? m2 : t;
    }
    out[row] = (int)(b1 & 8191u);
    if ((b2 >> 13) - (b1 >> 13) < TQ) {
        const int p = atomicAdd(cnt, 1);
        list[p] = row;
        res0[row] = ~0ull;
    }
}

// ---------------------------------------------------------------------------
// Refine: flagged rows, exact 3-product over all codes (verified structure).
// Block = 32 gathered rows x 1024-code strip (grid 1024 x 8, uniform exit).
// A rows converted from raw fp32 on the fly (same RTN split as prep).
// ---------------------------------------------------------------------------
__global__ __launch_bounds__(256, 1)
void refine_kernel(const float* __restrict__ X,
                   const uint4* __restrict__ Eh, const uint4* __restrict__ El,
                   const float* __restrict__ esqb, const int* __restrict__ cnt,
                   const int* __restrict__ list, unsigned long long* __restrict__ res0) {
    __shared__ int  rows_s[32];
    __shared__ uint4 sAh[1024], sAl[1024];   // 32 KB

    const int n = *cnt;
    const int base = blockIdx.x * 32;
    if (base >= n) return;                   // block-uniform
    const int tid = threadIdx.x;
    if (tid < 32) { const int j = base + tid; rows_s[tid] = list[j < n ? j : base]; }
    __syncthreads();

    // gather + split A: granule slot Lg (0..31) x row slot rr (0..31)
#pragma unroll
    for (int jj = 0; jj < 4; ++jj) {
        const int gg = jj * 256 + tid, Lg = gg >> 5, rr = gg & 31;
        const int row = rows_s[rr];
        const float* p = X + (size_t)row * D_DIM + Lg * 8;
        const float4 a = *(const float4*)p, b = *(const float4*)(p + 4);
        uint4 hi, lo; cvt_rtn(a, b, hi, lo);
        sAh[Lg * 32 + rr] = hi; sAl[Lg * 32 + rr] = lo;
    }
    __syncthreads();

    const int lane = tid & 63, wv = tid >> 6, l31 = lane & 31, lh = lane >> 5;
    const int cbase = blockIdx.y * 1024 + wv * 256;

    float bestv[16]; int besti[16];
#pragma unroll
    for (int r = 0; r < 16; ++r) { bestv[r] = 3.0e38f; besti[r] = 0; }

#pragma unroll 1
    for (int ps = 0; ps < 2; ++ps) {         // 2 passes of 128 codes
        const int c0 = cbase + ps * 128;
        f32x16 acc[4];
#pragma unroll
        for (int tj = 0; tj < 4; ++tj)
#pragma unroll
            for (int i = 0; i < 16; ++i) acc[tj][i] = 0.0f;

#pragma unroll
        for (int ks = 0; ks < 16; ++ks) {
            const int Lg = ks * 2 + lh;
            f16x8 b0[4], b1[4];
#pragma unroll
            for (int tj = 0; tj < 4; ++tj) {
                const int c = c0 + tj * 32 + l31;
                const int eg = (c >> 8) * 8192 + Lg * 256 + (c & 255);
                b0[tj] = __builtin_bit_cast(f16x8, Eh[eg]);
                b1[tj] = __builtin_bit_cast(f16x8, El[eg]);
            }
            const f16x8 a0 = __builtin_bit_cast(f16x8, sAh[Lg * 32 + l31]);
            const f16x8 a1 = __builtin_bit_cast(f16x8, sAl[Lg * 32 + l31]);
#pragma unroll
            for (int tj = 0; tj < 4; ++tj) acc[tj] = MFMA32(a1, b0[tj], acc[tj]);
#pragma unroll
            for (int tj = 0; tj < 4; ++tj) acc[tj] = MFMA32(a0, b1[tj], acc[tj]);
#pragma unroll
            for (int tj = 0; tj < 4; ++tj) acc[tj] = MFMA32(a0, b0[tj], acc[tj]);
        }

#pragma unroll
        for (int tj = 0; tj < 4; ++tj) {
            const int c = c0 + tj * 32 + l31;
            const float eb = esqb[c];
#pragma unroll
            for (int r = 0; r < 16; ++r) {
                const float dv = fmaf(-2.0f, acc[tj][r], eb);
                if (dv < bestv[r]) { bestv[r] = dv; besti[r] = c; }
            }
        }
    }

#pragma unroll
    for (int r = 0; r < 16; ++r) {
        float v = bestv[r]; int bi = besti[r];
#pragma unroll
        for (int m = 16; m >= 1; m >>= 1) {
            const float ov = __shfl_xor(v, m, 32);
            const int   oi = __shfl_xor(bi, m, 32);
            if (ov < v || (ov == v && oi < bi)) { v = ov; bi = oi; }
        }
        if (l31 == 0) {
            const int rl = (r & 3) + 8 * (r >> 2) + 4 * lh;   // 0..31
            atomicMin(&res0[rows_s[rl]],
                      ((unsigned long long)__float_as_uint(v) << 32) | (unsigned)bi);
        }
    }
}

// ---------------------------------------------------------------------------
__global__ void finalize_kernel(const unsigned long long* __restrict__ res0,
                                const int* __restrict__ cnt, const int* __restrict__ list,
                                int* __restrict__ out) {
    const int i = blockIdx.x * 256 + threadIdx.x;
    if (i < *cnt) {
        const int row = list[i];
        out[row] = (int)(res0[row] & 0xFFFFFFFFull);
    }
}

// ---------------------------------------------------------------------------
// Fallback (round-4 verified): in-loop split, for small ws_size.
// ---------------------------------------------------------------------------
__global__ void prologue_fb(const float* __restrict__ E, float* __restrict__ esqb,
                            unsigned long long* __restrict__ packed) {
    const int t = blockIdx.x * 256 + threadIdx.x;
    if (t < N_ROWS) packed[t] = ~0ull;
    const int gw = t >> 6, lane = t & 63;
    const float4 v = ((const float4*)(E + (size_t)gw * D_DIM))[lane];
    float s = v.x * v.x + v.y * v.y + v.z * v.z + v.w * v.w;
#pragma unroll
    for (int off = 32; off; off >>= 1) s += __shfl_down(s, off, 64);
    if (lane == 0) esqb[gw] = s + 1024.0f;
}

__global__ __launch_bounds__(256, 2)
void vq_mfma_fallback(const float* __restrict__ X, const float* __restrict__ E,
                      const float* __restrict__ esqb,
                      unsigned long long* __restrict__ packed) {
    __shared__ uint4 fXh[128 * 8], fXl[128 * 8];
    __shared__ uint4 fEh[128 * 8], fEl[128 * 8];
    __shared__ float fEsq[2048];

    const int tid  = threadIdx.x;
    const int lane = tid & 63;
    const int wv   = tid >> 6;
    const int wr   = wv >> 1, wc = wv & 1;
    const int l31  = lane & 31;
    const int lh   = lane >> 5;
    const int row0 = blockIdx.x * 128;
    const int cs0  = blockIdx.y * 2048;

#pragma unroll
    for (int i = 0; i < 8; ++i) fEsq[tid + 256 * i] = esqb[cs0 + tid + 256 * i];

    const int sr = tid >> 3, sg = tid & 7;

    float best[2][16]; int bidx[2][16];
#pragma unroll
    for (int ti = 0; ti < 2; ++ti)
#pragma unroll
        for (int r = 0; r < 16; ++r) { best[ti][r] = 3.0e38f; bidx[ti][r] = 0; }

    f32x16 acc[2][2];

#pragma unroll 1
    for (int ct = 0; ct < 16; ++ct) {
#pragma unroll
        for (int ti = 0; ti < 2; ++ti)
#pragma unroll
            for (int tj = 0; tj < 2; ++tj)
#pragma unroll
                for (int i = 0; i < 16; ++i) acc[ti][tj][i] = 0.0f;

#pragma unroll 1
        for (int dc = 0; dc < 4; ++dc) {
            __syncthreads();
#pragma unroll
            for (int i = 0; i < 4; ++i) {
                const int r = 32 * i + sr;
                const float* p = X + (size_t)(row0 + r) * D_DIM + dc * 64 + sg * 8;
                const float4 a = *(const float4*)p, b = *(const float4*)(p + 4);
                uint4 hi, lo; cvt_granule(a, b, hi, lo);
                const int o = r * 8 + (sg ^ (r & 7));
                fXh[o] = hi; fXl[o] = lo;
            }
#pragma unroll
            for (int i = 0; i < 4; ++i) {
                const int r = 32 * i + sr;
                const float* p = E + (size_t)(cs0 + ct * 128 + r) * D_DIM + dc * 64 + sg * 8;
                const float4 a = *(const float4*)p, b = *(const float4*)(p + 4);
                uint4 hi, lo; cvt_granule(a, b, hi, lo);
                const int o = r * 8 + (sg ^ (r & 7));
                fEh[o] = hi; fEl[o] = lo;
            }
            __syncthreads();

#pragma unroll
            for (int s = 0; s < 4; ++s) {
                const int gi = s * 2 + lh;
                f16x8 axh[2], axl[2], beh[2], bel[2];
#pragma unroll
                for (int ti = 0; ti < 2; ++ti) {
                    const int r = wr * 64 + ti * 32 + l31;
                    const int o = r * 8 + (gi ^ (r & 7));
                    axh[ti] = __builtin_bit_cast(f16x8, fXh[o]);
                    axl[ti] = __builtin_bit_cast(f16x8, fXl[o]);
                }
#pragma unroll
                for (int tj = 0; tj < 2; ++tj) {
                    const int c = wc * 64 + tj * 32 + l31;
                    const int o = c * 8 + (gi ^ (c & 7));
                    beh[tj] = __builtin_bit_cast(f16x8, fEh[o]);
                    bel[tj] = __builtin_bit_cast(f16x8, fEl[o]);
                }
#pragma unroll
                for (int ti = 0; ti < 2; ++ti)
#pragma unroll
                    for (int tj = 0; tj < 2; ++tj) {
                        acc[ti][tj] = MFMA32(axl[ti], beh[tj], acc[ti][tj]);
                        acc[ti][tj] = MFMA32(axh[ti], bel[tj], acc[ti][tj]);
                        acc[ti][tj] = MFMA32(axh[ti], beh[tj], acc[ti][tj]);
                    }
            }
        }

#pragma unroll
        for (int tj = 0; tj < 2; ++tj) {
            const int cloc = ct * 128 + wc * 64 + tj * 32 + l31;
            const float eb = fEsq[cloc];
            const int  code = cs0 + cloc;
#pragma unroll
            for (int ti = 0; ti < 2; ++ti)
#pragma unroll
                for (int r = 0; r < 16; ++r) {
                    const float dv = fmaf(-2.0f, acc[ti][tj][r], eb);
                    if (dv < best[ti][r]) { best[ti][r] = dv; bidx[ti][r] = code; }
                }
        }
    }

#pragma unroll
    for (int ti = 0; ti < 2; ++ti)
#pragma unroll
        for (int r = 0; r < 16; ++r) {
            float b = best[ti][r]; int bi = bidx[ti][r];
#pragma unroll
            for (int m = 16; m >= 1; m >>= 1) {
                const float ov = __shfl_xor(b, m, 32);
                const int   oi = __shfl_xor(bi, m, 32);
                if (ov < b || (ov == b && oi < bi)) { b = ov; bi = oi; }
            }
            if (l31 == 0) {
                const int row = row0 + wr * 64 + ti * 32 + (r & 3) + 8 * (r >> 2) + 4 * lh;
                const unsigned long long p =
                    ((unsigned long long)__float_as_uint(b) << 32) | (unsigned)bi;
                atomicMin(&packed[row], p);
            }
        }
}

__global__ void finish_fb(const unsigned long long* __restrict__ packed,
                          int* __restrict__ out) {
    const int i = blockIdx.x * 256 + threadIdx.x;
    out[i] = (int)(unsigned)(packed[i] & 0xffffffffull);
}

// ---------------------------------------------------------------------------
extern "C" void kernel_launch(void* const* d_in, const int* in_sizes, int n_in,
                              void* d_out, int out_size, void* d_ws, size_t ws_size,
                              hipStream_t stream) {
    const float* X = (const float*)d_in[0];    // [32768, 256]
    const float* E = (const float*)d_in[1];    // [8192, 256]
    char* ws = (char*)d_ws;
    int* out = (int*)d_out;

    float* esqb = (float*)ws;                                    // 32 KB @ 0
    uint2* res  = (uint2*)(ws + 32768);                          // 1 MB (4 strips)
    unsigned long long* res0 = (unsigned long long*)(ws + 1081344); // 256 KB
    int* cnt  = (int*)(ws + 1343488);                            // 16 B
    int* list = (int*)(ws + 1343504);                            // 128 KB
    const size_t base = 1572864;                                 // 1.5 MB
    const size_t szX  = (size_t)N_ROWS * D_DIM * 2;              // 16 MB (hi only)
    const size_t szE  = (size_t)K_CODES * D_DIM * 2;             // 4 MB per half
    const size_t need = base + szX + 2 * szE;                    // ~25.5 MB

    if (ws_size >= need) {
        uint4* Xh = (uint4*)(ws + base);
        uint4* Eh = (uint4*)(ws + base + szX);
        uint4* El = (uint4*)(ws + base + szX + szE);
        prep_kernel<<<dim3(3328), dim3(256), 0, stream>>>(X, E, Xh, Eh, El, esqb, cnt);
        vq_pass1<<<dim3(N_ROWS / 128, 4), dim3(256), 0, stream>>>(Xh, Eh, esqb, res);
        merge_kernel<<<dim3(N_ROWS / 256), dim3(256), 0, stream>>>(res, res0, out, cnt, list);
        refine_kernel<<<dim3(1024, 8), dim3(256), 0, stream>>>(X, Eh, El, esqb,
                                                               cnt, list, res0);
        finalize_kernel<<<dim3(N_ROWS / 256), dim3(256), 0, stream>>>(res0, cnt, list, out);
    } else {
        unsigned long long* packed = (unsigned long long*)(ws + 32768);
        prologue_fb<<<dim3(2048), dim3(256), 0, stream>>>(E, esqb, packed);
        vq_mfma_fallback<<<dim3(N_ROWS / 128, 4), dim3(256), 0, stream>>>(X, E, esqb, packed);
        finish_fb<<<dim3(N_ROWS / 256), dim3(256), 0, stream>>>(packed, out);
    }
}